// Round 7
// baseline (387.130 us; speedup 1.0000x reference)
//
#include <hip/hip_runtime.h>
#include <stdint.h>

#define S_TOK 16384
#define M_DIM 512
#define E_EXP 16
#define D_OUT 256
#define H1D 500
#define H2D 500
#define H3D 1000

typedef float f32x4 __attribute__((ext_vector_type(4)));
typedef long lx2 __attribute__((ext_vector_type(2)));   // 16 B = two fp8 fragments
typedef int i32x2 __attribute__((ext_vector_type(2)));

template <bool HI>
__device__ __forceinline__ int pk8(float a, float b, int old) {
  return __builtin_amdgcn_cvt_pk_fp8_f32(a, b, old, HI);
}
__device__ __forceinline__ unsigned char f2fp8(float f) {
  return (unsigned char)(__builtin_amdgcn_cvt_pk_fp8_f32(f, 0.f, 0, false) & 0xff);
}

// async global->LDS, 16B per lane; LDS dest = wave-uniform base + lane*16
__device__ __forceinline__ void ld_lds16(const unsigned char* g, unsigned char* l) {
  __builtin_amdgcn_global_load_lds(
      (const __attribute__((address_space(1))) unsigned int*)(const void*)g,
      (__attribute__((address_space(3))) unsigned int*)(void*)l, 16, 0, 0);
}

// fused waitcnt+barrier: nothing can slip between the count-wait and the barrier.
// Control flow is block-uniform at every call site.
__device__ __forceinline__ void barrier_vm8() { asm volatile("s_waitcnt vmcnt(8)\n\ts_barrier" ::: "memory"); }
__device__ __forceinline__ void barrier_vm6() { asm volatile("s_waitcnt vmcnt(6)\n\ts_barrier" ::: "memory"); }
__device__ __forceinline__ void barrier_vm4() { asm volatile("s_waitcnt vmcnt(4)\n\ts_barrier" ::: "memory"); }
__device__ __forceinline__ void barrier_vm3() { asm volatile("s_waitcnt vmcnt(3)\n\ts_barrier" ::: "memory"); }
__device__ __forceinline__ void barrier_vm0() { asm volatile("s_waitcnt vmcnt(0)\n\ts_barrier" ::: "memory"); }
__device__ __forceinline__ void barrier_lgkm0() { asm volatile("s_waitcnt lgkmcnt(0)\n\ts_barrier" ::: "memory"); }

struct TokenRec { int i1, i2; float g1, g2; };

// ---------------- FUSED router + weight-convert (independent workloads, one dispatch)
// INTERLEAVED 1-in-6: block b with b%6==5 is a router block (1024 total), the rest
// are convw blocks (5120) -- router's f64-VALU work co-schedules with convw's
// memory-bound streaming across the whole dispatch timeline instead of trailing it.
__global__ __launch_bounds__(256) void k_router_convw(const float* __restrict__ x,
                                                      const float* __restrict__ noise,
                                                      const float* __restrict__ Wr,
                                                      float* __restrict__ sel_out,
                                                      float* __restrict__ sel_buf,
                                                      TokenRec* __restrict__ te,
                                                      const float* __restrict__ W1,
                                                      const float* __restrict__ W2,
                                                      const float* __restrict__ W3,
                                                      const float* __restrict__ W4,
                                                      unsigned char* __restrict__ D1,
                                                      unsigned char* __restrict__ D2,
                                                      unsigned char* __restrict__ D3,
                                                      unsigned char* __restrict__ D4) {
  __shared__ float smem[E_EXP * 516];   // 33 KB: router wr[] / convw tile[64][65]
  int t = threadIdx.x;
  int r6 = blockIdx.x / 6, m6 = blockIdx.x % 6;

  if (m6 != 5) {
    // ================= convw body =================
    float (*tile)[65] = (float(*)[65])smem;   // tile[k_local][n_local], pad 65
    int cid = r6 * 5 + m6;                    // 0..5119
    int tb = cid % 320, e = cid / 320;
    const float* src; unsigned char* dst;
    int Kr, Nr, Kp, Np, kx, ny;
    if (tb < 64)        { src = W1; dst = D1; Kr = 512;  Nr = H1D; Kp = 512;  Np = 512;  kx = tb >> 3;  ny = tb & 7; }
    else if (tb < 128)  { tb -= 64;  src = W2; dst = D2; Kr = H1D; Nr = H2D; Kp = 512;  Np = 512;  kx = tb >> 3;  ny = tb & 7; }
    else if (tb < 256)  { tb -= 128; src = W3; dst = D3; Kr = H2D; Nr = H3D; Kp = 512;  Np = 1024; kx = tb >> 4;  ny = tb & 15; }
    else                { tb -= 256; src = W4; dst = D4; Kr = H3D; Nr = 256; Kp = 1024; Np = 256;  kx = tb >> 2;  ny = tb & 3; }
    int k0 = kx * 64, n0 = ny * 64;
    const float* sp = src + (size_t)e * Kr * Nr;
    // vectorized staging: 4 x f32x4 per thread (16 lanes x 4 floats = 64 n per row)
    int ry4 = t >> 4, cx4 = (t & 15) * 4;
#pragma unroll
    for (int i = 0; i < 4; i++) {
      int k = k0 + ry4 + i * 16, n = n0 + cx4;
      f32x4 v;
      if (k < Kr && n + 3 < Nr) {
        v = *(const f32x4*)&sp[(size_t)k * Nr + n];
      } else {
        v.x = (k < Kr && n + 0 < Nr) ? sp[(size_t)k * Nr + n + 0] : 0.f;
        v.y = (k < Kr && n + 1 < Nr) ? sp[(size_t)k * Nr + n + 1] : 0.f;
        v.z = (k < Kr && n + 2 < Nr) ? sp[(size_t)k * Nr + n + 2] : 0.f;
        v.w = (k < Kr && n + 3 < Nr) ? sp[(size_t)k * Nr + n + 3] : 0.f;
      }
      int r = ry4 + i * 16;
      tile[r][cx4 + 0] = v.x; tile[r][cx4 + 1] = v.y;
      tile[r][cx4 + 2] = v.z; tile[r][cx4 + 3] = v.w;
    }
    __syncthreads();
    int nl = t >> 2, q = t & 3;
    int b0 = pk8<false>(tile[q * 8 + 0][nl], tile[q * 8 + 1][nl], 0);
    b0 = pk8<true>(tile[q * 8 + 2][nl], tile[q * 8 + 3][nl], b0);
    int b1 = pk8<false>(tile[q * 8 + 4][nl], tile[q * 8 + 5][nl], 0);
    b1 = pk8<true>(tile[q * 8 + 6][nl], tile[q * 8 + 7][nl], b1);
    int c0 = pk8<false>(tile[32 + q * 8 + 0][nl], tile[32 + q * 8 + 1][nl], 0);
    c0 = pk8<true>(tile[32 + q * 8 + 2][nl], tile[32 + q * 8 + 3][nl], c0);
    int c1 = pk8<false>(tile[32 + q * 8 + 4][nl], tile[32 + q * 8 + 5][nl], 0);
    c1 = pk8<true>(tile[32 + q * 8 + 6][nl], tile[32 + q * 8 + 7][nl], c1);
    uint4 pk; pk.x = (unsigned)b0; pk.y = (unsigned)b1; pk.z = (unsigned)c0; pk.w = (unsigned)c1;
    *(uint4*)&dst[(size_t)e * Np * Kp + (size_t)(n0 + nl) * Kp + k0 + q * 16] = pk;
    return;
  }

  // ================= router body =================
  float* wr = smem;                     // [E_EXP * 516], pad 516
  int rb = r6;                          // 0..1023
  for (int i = t; i < E_EXP * M_DIM; i += 256) {
    int e = i >> 9, m = i & 511;
    wr[e * 516 + m] = Wr[i];
  }
  __syncthreads();

  int wv = t >> 6, l = t & 63;
  int e = l & 15, tg = l >> 4;
  int s = rb * 16 + wv * 4 + tg;

  const float* xr = x + (size_t)s * M_DIM;
  const float* wre = &wr[e * 516];
  double a0 = 0.0, a1 = 0.0, a2 = 0.0, a3 = 0.0;
#pragma unroll 4
  for (int m = 0; m < M_DIM; m += 4) {
    f32x4 xv = *(const f32x4*)(xr + m);
    f32x4 wv4 = *(const f32x4*)(wre + m);
    a0 += (double)xv.x * (double)wv4.x;
    a1 += (double)xv.y * (double)wv4.y;
    a2 += (double)xv.z * (double)wv4.z;
    a3 += (double)xv.w * (double)wv4.w;
  }
  double a = (a0 + a1) + (a2 + a3);
  a += (double)noise[(size_t)s * E_EXP + e];

  double mx = a;
#pragma unroll
  for (int off = 8; off >= 1; off >>= 1) { double o = __shfl_xor(mx, off, 64); mx = (o > mx) ? o : mx; }
  double p = exp(a - mx);
  double sum = p;
#pragma unroll
  for (int off = 8; off >= 1; off >>= 1) sum += __shfl_xor(sum, off, 64);
  sel_buf[(size_t)s * E_EXP + e] = (float)(p / sum);

  unsigned long long pb = __double_as_longlong(p);
  unsigned long long key = (pb & ~0xFFull) | (unsigned long long)(255 - e);
  unsigned long long k1 = key;
#pragma unroll
  for (int off = 8; off >= 1; off >>= 1) { unsigned long long o = __shfl_xor(k1, off, 64); k1 = (o > k1) ? o : k1; }
  int i1 = 255 - (int)(k1 & 0xFFull);
  unsigned long long key2 = (e == i1) ? 0ull : key;
  unsigned long long k2 = key2;
#pragma unroll
  for (int off = 8; off >= 1; off >>= 1) { unsigned long long o = __shfl_xor(k2, off, 64); k2 = (o > k2) ? o : k2; }
  int i2 = 255 - (int)(k2 & 0xFFull);

  double p1 = __shfl(p, tg * 16 + i1, 64);
  double p2 = __shfl(p, tg * 16 + i2, 64);

  sel_out[(size_t)s * E_EXP + e] = (e == i1 || e == i2) ? 1.f : 0.f;
  if (e == 0) {
    double inv = 1.0 / (p1 + p2);
    TokenRec r; r.i1 = i1; r.i2 = i2; r.g1 = (float)(p1 * inv); r.g2 = (float)(p2 * inv);
    te[s] = r;
  }
}

// ---------------- stats: per-block proxy partial sums + histogram ----------------
__global__ __launch_bounds__(256) void k_stats(const float* __restrict__ sel_buf,
                                               const TokenRec* __restrict__ te,
                                               float* __restrict__ partials) {  // [16][32]
  __shared__ float psum[256];
  __shared__ unsigned int hist[E_EXP];
  int t = threadIdx.x, b = blockIdx.x;
  if (t < E_EXP) hist[t] = 0u;
  __syncthreads();
  int e = t & 15, rg = t >> 4;
  int base = b * 1024;
  float acc = 0.f;
#pragma unroll 4
  for (int i = 0; i < 64; i++)
    acc += sel_buf[(size_t)(base + i * 16 + rg) * E_EXP + e];
  for (int i = t; i < 1024; i += 256) {
    TokenRec r = te[base + i];
    atomicAdd(&hist[r.i1], 1u);
    atomicAdd(&hist[r.i2], 1u);
  }
  psum[t] = acc;
  __syncthreads();
  if (t < E_EXP) {
    float v = 0.f;
#pragma unroll
    for (int rg2 = 0; rg2 < 16; rg2++) v += psum[rg2 * 16 + t];
    partials[b * 32 + t] = v;
    partials[b * 32 + 16 + t] = (float)hist[t];
  }
}

// ---------------- reduce partials -> counts/offsets + balance loss + cursor init ------
__global__ void k_prefix_loss(const float* __restrict__ partials,
                              unsigned int* __restrict__ counts,
                              unsigned int* __restrict__ offsets,
                              unsigned int* __restrict__ cursor,
                              float* __restrict__ out_loss) {
  __shared__ float pr[E_EXP];
  __shared__ unsigned int cn[E_EXP];
  int t = threadIdx.x;
  if (t < E_EXP) {
    float p = 0.f, c = 0.f;
    for (int b = 0; b < 16; b++) { p += partials[b * 32 + t]; c += partials[b * 32 + 16 + t]; }
    pr[t] = p; cn[t] = (unsigned int)(c + 0.5f);
    cursor[t] = 0u;
  }
  __syncthreads();
  if (t == 0) {
    unsigned int acc = 0; float ls = 0.f;
    for (int e = 0; e < E_EXP; e++) {
      counts[e] = cn[e];
      offsets[e] = acc;
      acc += cn[e];
      ls += pr[e] * (float)cn[e];
    }
    out_loss[0] = ls * ((float)E_EXP / ((float)S_TOK * (float)S_TOK));
    out_loss[1] = 0.f;
  }
}

// ---------------- listbuild: block-level reservation + inverse map ----------------
__global__ __launch_bounds__(256) void k_listbuild(const TokenRec* __restrict__ te,
                                                   const unsigned int* __restrict__ offsets,
                                                   unsigned int* __restrict__ cursor,
                                                   int* __restrict__ slot_token,
                                                   float* __restrict__ slot_gate,
                                                   int* __restrict__ tok_slot) {
  __shared__ unsigned int lhist[E_EXP];
  __shared__ unsigned int lbase[E_EXP];
  __shared__ unsigned int lcur[E_EXP];
  int t = threadIdx.x, b = blockIdx.x;
  int base = b * 1024;
  if (t < E_EXP) lhist[t] = 0u;
  __syncthreads();
  for (int i = t; i < 1024; i += 256) {
    TokenRec r = te[base + i];
    atomicAdd(&lhist[r.i1], 1u);
    atomicAdd(&lhist[r.i2], 1u);
  }
  __syncthreads();
  if (t < E_EXP) {
    lbase[t] = offsets[t] + atomicAdd(&cursor[t], lhist[t]);
    lcur[t] = 0u;
  }
  __syncthreads();
  for (int i = t; i < 1024; i += 256) {
    int s = base + i;
    TokenRec r = te[s];
    unsigned int p1 = atomicAdd(&lcur[r.i1], 1u);
    int sl1 = (int)(lbase[r.i1] + p1);
    slot_token[sl1] = s; slot_gate[sl1] = r.g1;
    unsigned int p2 = atomicAdd(&lcur[r.i2], 1u);
    int sl2 = (int)(lbase[r.i2] + p2);
    slot_token[sl2] = s; slot_gate[sl2] = r.g2;
    tok_slot[2 * s] = sl1;
    tok_slot[2 * s + 1] = sl2;
  }
}

// ---------------- gather x rows -> fp8 compact activations (k-interleaved) ----------
// within each 64-k block: byte = q*16 + h*8 + j  <->  k = h*32 + q*8 + j
__global__ __launch_bounds__(256) void k_gather(const float* __restrict__ x,
                                                const int* __restrict__ slot_token,
                                                unsigned char* __restrict__ xg) {
  int idx = blockIdx.x * 256 + threadIdx.x;   // 32768 * 64
  int row = idx >> 6, t6 = idx & 63;
  int blk = t6 >> 3, q = (t6 >> 1) & 3, h = t6 & 1;
  int tkn = slot_token[row];
  const float* xp = x + (size_t)tkn * M_DIM + blk * 64 + h * 32 + q * 8;
  f32x4 v0 = *(const f32x4*)xp;
  f32x4 v1 = *(const f32x4*)(xp + 4);
  int b0 = pk8<false>(v0.x, v0.y, 0); b0 = pk8<true>(v0.z, v0.w, b0);
  int b1 = pk8<false>(v1.x, v1.y, 0); b1 = pk8<true>(v1.z, v1.w, b1);
  i32x2 o; o.x = b0; o.y = b1;
  *(i32x2*)&xg[(size_t)row * 512 + blk * 64 + q * 16 + h * 8] = o;
}

// ---------------- grouped GEMM (fp8, BK=64): 128x128 tile, 3-buffer depth-2 async
// staging (prefetch distance 2, steady-state wait vmcnt(8) -- two K-steps in flight
// per thread, covering L2/HBM latency; tail vm4/vm0). XOR-swizzled 16-B segments
// (0 conflicts). SWAPPED operands: A=weights, B=acts. LDS epilogue (coalesced
// dwordx4 stores). mid: out = relu(in @ W^T + b) -> fp8 (pad cols zeroed)
__global__ __launch_bounds__(256, 3) void k_gemm_mid(const unsigned char* __restrict__ in,
                                                  const unsigned char* __restrict__ wt,
                                                  const float* __restrict__ bias,
                                                  unsigned char* __restrict__ out,
                                                  const unsigned int* __restrict__ offsets,
                                                  const unsigned int* __restrict__ counts,
                                                  int KP, int NP, int NREAL) {
  int e = blockIdx.z;
  int n_e = (int)counts[e];
  if (n_e == 0) return;
  int base = (int)offsets[e];
  int bn = blockIdx.y;
  __shared__ __align__(16) unsigned char As[3][128 * 64];  // 3 x 8 KB activations (+ epilogue tile)
  __shared__ __align__(16) unsigned char Bs[3][128 * 64];  // 3 x 8 KB weights
  int t = threadIdx.x;
  int w = t >> 6, l = t & 63;
  int wm = w & 1, wn = w >> 1;
  int lr = l & 15, lq = l >> 4;
  int r_ = l >> 2, s_ = l & 3;
  int s2 = s_ ^ ((r_ >> 1) & 3);               // swizzled source segment (16 B units)
  int rsw = (lq ^ ((lr >> 1) & 3)) * 16;       // read-side swizzled byte offset
  int c0 = 2 * w, c1 = 2 * w + 1;              // two 16-row chunks per wave

  const unsigned char* bW = wt + (size_t)e * NP * KP;
  const unsigned char* bs0 = bW + (size_t)(bn * 128 + c0 * 16 + r_) * KP + s2 * 16;
  const unsigned char* bs1 = bW + (size_t)(bn * 128 + c1 * 16 + r_) * KP + s2 * 16;
  int nk = KP >> 6;

  for (int bm = blockIdx.x; bm * 128 < n_e; bm += gridDim.x) {
    int ra = bm * 128 + c0 * 16 + r_; ra = (ra < n_e) ? ra : (n_e - 1);
    int rb = bm * 128 + c1 * 16 + r_; rb = (rb < n_e) ? rb : (n_e - 1);
    const unsigned char* a0 = in + (size_t)(base + ra) * KP + s2 * 16;
    const unsigned char* a1 = in + (size_t)(base + rb) * KP + s2 * 16;
    const unsigned char* b0 = bs0;
    const unsigned char* b1 = bs1;
    f32x4 acc[4][4];
#pragma unroll
    for (int i = 0; i < 4; i++)
#pragma unroll
      for (int j = 0; j < 4; j++) acc[i][j] = (f32x4){0.f, 0.f, 0.f, 0.f};

    // prologue: stage K-tiles 0 and 1 (8 loads in flight per thread)
#pragma unroll
    for (int tt = 0; tt < 2; tt++) {
      ld_lds16(a0, &As[tt][c0 * 1024]); ld_lds16(a1, &As[tt][c1 * 1024]);
      ld_lds16(b0, &Bs[tt][c0 * 1024]); ld_lds16(b1, &Bs[tt][c1 * 1024]);
      a0 += 64; a1 += 64; b0 += 64; b1 += 64;
    }

    for (int ks = 0; ks < nk; ks++) {
      int cb = ks % 3;
      // stage K-tile ks+2 (distance 2), then wait only until tile ks's 4 loads
      // are complete: the 8 loads of tiles ks+1, ks+2 stay in flight (T4 deep).
      if (ks + 2 < nk) {
        int sb = (ks + 2) % 3;
        ld_lds16(a0, &As[sb][c0 * 1024]); ld_lds16(a1, &As[sb][c1 * 1024]);
        ld_lds16(b0, &Bs[sb][c0 * 1024]); ld_lds16(b1, &Bs[sb][c1 * 1024]);
        a0 += 64; a1 += 64; b0 += 64; b1 += 64;
        barrier_vm8();
      } else if (ks + 1 < nk) {
        barrier_vm4();
      } else {
        barrier_vm0();
      }
      // buf[cb] fully staged by all waves
      lx2 af[4], wf[4];
#pragma unroll
      for (int mi = 0; mi < 4; mi++) af[mi] = *(const lx2*)&As[cb][(wm * 64 + mi * 16 + lr) * 64 + rsw];
#pragma unroll
      for (int ni = 0; ni < 4; ni++) wf[ni] = *(const lx2*)&Bs[cb][(wn * 64 + ni * 16 + lr) * 64 + rsw];
      __builtin_amdgcn_s_setprio(1);
#pragma unroll
      for (int ni = 0; ni < 4; ni++)
#pragma unroll
        for (int mi = 0; mi < 4; mi++) {
          acc[ni][mi] = __builtin_amdgcn_mfma_f32_16x16x32_fp8_fp8(wf[ni].x, af[mi].x, acc[ni][mi], 0, 0, 0);
          acc[ni][mi] = __builtin_amdgcn_mfma_f32_16x16x32_fp8_fp8(wf[ni].y, af[mi].y, acc[ni][mi], 0, 0, 0);
        }
      __builtin_amdgcn_s_setprio(0);
      // all waves done reading buf[cb] before the staging issued next step overwrites it
      barrier_lgkm0();
    }

    // ---- epilogue via LDS: pack quads -> swizzled LDS tile -> coalesced 16B stores
    unsigned char* eb = &As[0][0];   // 16 KB window over As[0..1]: [row 0..127][byte 0..127]
#pragma unroll
    for (int ni = 0; ni < 4; ni++) {
      int nl = wn * 64 + ni * 16 + lq * 4;       // local col (0..127), 4-aligned
      int n0 = bn * 128 + nl;                    // global col
      bool cok = n0 < NREAL;                     // NREAL % 4 == 0 -> whole quad in/out
      f32x4 bv = (f32x4){0.f, 0.f, 0.f, 0.f};
      if (cok) bv = *(const f32x4*)&bias[(size_t)e * NREAL + n0];
      int k6 = nl & 63;
      int off = ((nl >> 6) << 6) + ((k6 >> 3) & 3) * 16 + ((k6 >> 5) & 1) * 8 + (k6 & 7);
#pragma unroll
      for (int mi = 0; mi < 4; mi++) {
        int row = wm * 64 + mi * 16 + lr;        // local row 0..127
        unsigned int pkv = 0u;
        if (cok) {
          f32x4 v = acc[ni][mi];
          int p = pk8<false>(fmaxf(v.x + bv.x, 0.f), fmaxf(v.y + bv.y, 0.f), 0);
          p = pk8<true>(fmaxf(v.z + bv.z, 0.f), fmaxf(v.w + bv.w, 0.f), p);
          pkv = (unsigned int)p;
        }
        *(unsigned int*)&eb[row * 128 + (off ^ ((row & 7) << 4))] = pkv;
      }
    }
    barrier_lgkm0();   // tile complete in LDS
    // coalesced sweep: 1024 x 16B; lanes cover consecutive segments -> full lines
#pragma unroll
    for (int it = 0; it < 4; it++) {
      int idx = it * 256 + t;
      int row = idx >> 3, seg = idx & 7;
      uint4 val = *(const uint4*)&eb[row * 128 + ((seg * 16) ^ ((row & 7) << 4))];
      int m = bm * 128 + row;
      if (m < n_e)
        *(uint4*)&out[(size_t)(base + m) * NP + bn * 128 + seg * 16] = val;
    }
    __syncthreads();   // epilogue LDS reads done before next tile's staging overwrites As
  }
}

// fin: 128x64 tile, swapped operands; 3-buffer depth-2 staging (vm6/vm3/vm0);
// eo[slot] = gate * (h3 @ W4 + b4); float4 stores.
__global__ __launch_bounds__(256, 4) void k_gemm_fin(const unsigned char* __restrict__ in,
                                                  const unsigned char* __restrict__ wt,
                                                  const float* __restrict__ bias,
                                                  float* __restrict__ eo,
                                                  const unsigned int* __restrict__ offsets,
                                                  const unsigned int* __restrict__ counts,
                                                  const float* __restrict__ slot_gate) {
  const int KP = 1024, NP = 256;
  int e = blockIdx.z;
  int n_e = (int)counts[e];
  if (n_e == 0) return;
  int base = (int)offsets[e];
  int bn = blockIdx.y;
  __shared__ __align__(16) unsigned char As[3][128 * 64];  // 3 x 8 KB activations
  __shared__ __align__(16) unsigned char Bs[3][64 * 64];   // 3 x 4 KB weights
  int t = threadIdx.x;
  int w = t >> 6, l = t & 63;
  int wm = w & 1, wn = w >> 1;
  int lr = l & 15, lq = l >> 4;
  int r_ = l >> 2, s_ = l & 3;
  int s2 = s_ ^ ((r_ >> 1) & 3);
  int rsw = (lq ^ ((lr >> 1) & 3)) * 16;
  int c0 = 2 * w, c1 = 2 * w + 1;

  const unsigned char* bW = wt + (size_t)e * NP * KP;
  const unsigned char* bsrc = bW + (size_t)(bn * 64 + w * 16 + r_) * KP + s2 * 16;
  int nk = KP >> 6;

  for (int bm = blockIdx.x; bm * 128 < n_e; bm += gridDim.x) {
    int ra = bm * 128 + c0 * 16 + r_; ra = (ra < n_e) ? ra : (n_e - 1);
    int rb = bm * 128 + c1 * 16 + r_; rb = (rb < n_e) ? rb : (n_e - 1);
    const unsigned char* a0 = in + (size_t)(base + ra) * KP + s2 * 16;
    const unsigned char* a1 = in + (size_t)(base + rb) * KP + s2 * 16;
    const unsigned char* bq = bsrc;
    f32x4 acc[2][4];
#pragma unroll
    for (int i = 0; i < 2; i++)
#pragma unroll
      for (int j = 0; j < 4; j++) acc[i][j] = (f32x4){0.f, 0.f, 0.f, 0.f};

#pragma unroll
    for (int tt = 0; tt < 2; tt++) {
      ld_lds16(a0, &As[tt][c0 * 1024]); ld_lds16(a1, &As[tt][c1 * 1024]);
      ld_lds16(bq, &Bs[tt][w * 1024]);
      a0 += 64; a1 += 64; bq += 64;
    }

    for (int ks = 0; ks < nk; ks++) {
      int cb = ks % 3;
      if (ks + 2 < nk) {
        int sb = (ks + 2) % 3;
        ld_lds16(a0, &As[sb][c0 * 1024]); ld_lds16(a1, &As[sb][c1 * 1024]);
        ld_lds16(bq, &Bs[sb][w * 1024]);
        a0 += 64; a1 += 64; bq += 64;
        barrier_vm6();
      } else if (ks + 1 < nk) {
        barrier_vm3();
      } else {
        barrier_vm0();
      }
      lx2 af[4], wf[2];
#pragma unroll
      for (int mi = 0; mi < 4; mi++) af[mi] = *(const lx2*)&As[cb][(wm * 64 + mi * 16 + lr) * 64 + rsw];
#pragma unroll
      for (int ni = 0; ni < 2; ni++) wf[ni] = *(const lx2*)&Bs[cb][(wn * 32 + ni * 16 + lr) * 64 + rsw];
      __builtin_amdgcn_s_setprio(1);
#pragma unroll
      for (int ni = 0; ni < 2; ni++)
#pragma unroll
        for (int mi = 0; mi < 4; mi++) {
          acc[ni][mi] = __builtin_amdgcn_mfma_f32_16x16x32_fp8_fp8(wf[ni].x, af[mi].x, acc[ni][mi], 0, 0, 0);
          acc[ni][mi] = __builtin_amdgcn_mfma_f32_16x16x32_fp8_fp8(wf[ni].y, af[mi].y, acc[ni][mi], 0, 0, 0);
        }
      __builtin_amdgcn_s_setprio(0);
      barrier_lgkm0();
    }

    int mbase = bm * 128 + wm * 64;
    int nbase = bn * 64 + wn * 32;
#pragma unroll
    for (int ni = 0; ni < 2; ni++) {
      int n0 = nbase + ni * 16 + lq * 4;
      f32x4 bv = *(const f32x4*)&bias[(size_t)e * 256 + n0];
#pragma unroll
      for (int mi = 0; mi < 4; mi++) {
        int m = mbase + mi * 16 + lr;
        if (m < n_e) {
          int gr = base + m;
          float g = slot_gate[gr];
          f32x4 v;
          v.x = g * (acc[ni][mi].x + bv.x);
          v.y = g * (acc[ni][mi].y + bv.y);
          v.z = g * (acc[ni][mi].z + bv.z);
          v.w = g * (acc[ni][mi].w + bv.w);
          *(f32x4*)&eo[(size_t)gr * NP + n0] = v;
        }
      }
    }
  }
}

// ---------------- combine: out[s] = eo[sl1(s)] + eo[sl2(s)] ----------------
__global__ __launch_bounds__(256) void k_combine(const float* __restrict__ eo,
                                                 const int* __restrict__ tok_slot,
                                                 float* __restrict__ out) {
  int idx = blockIdx.x * 256 + threadIdx.x;
  int s = idx >> 6, q = idx & 63;
  int sl1 = tok_slot[2 * s], sl2 = tok_slot[2 * s + 1];
  f32x4 v1 = *(const f32x4*)&eo[(size_t)sl1 * D_OUT + q * 4];
  f32x4 v2 = *(const f32x4*)&eo[(size_t)sl2 * D_OUT + q * 4];
  *(f32x4*)&out[(size_t)s * D_OUT + q * 4] = v1 + v2;
}

extern "C" void kernel_launch(void* const* d_in, const int* in_sizes, int n_in,
                              void* d_out, int out_size, void* d_ws, size_t ws_size,
                              hipStream_t stream) {
  const float* x    = (const float*)d_in[0];
  const float* nois = (const float*)d_in[1];
  const float* Wr   = (const float*)d_in[2];
  const float* W1   = (const float*)d_in[3];
  const float* b1   = (const float*)d_in[4];
  const float* W2   = (const float*)d_in[5];
  const float* b2   = (const float*)d_in[6];
  const float* W3   = (const float*)d_in[7];
  const float* b3   = (const float*)d_in[8];
  const float* W4   = (const float*)d_in[9];
  const float* b4   = (const float*)d_in[10];
  float* out = (float*)d_out;

  char* w = (char*)d_ws;
  unsigned char* actA = (unsigned char*)(w + 0);          // 32768*1024 fp8 = 33554432 B
  unsigned char* actB = (unsigned char*)(w + 33554432);   // 32768*512 fp8  = 16777216 B
  unsigned char* Wt1  = (unsigned char*)(w + 50331648);   // 16*512*512   = 4 MB
  unsigned char* Wt2  = (unsigned char*)(w + 54525952);   // 4 MB
  unsigned char* Wt3  = (unsigned char*)(w + 58720256);   // 16*1024*512  = 8 MB
  unsigned char* Wt4  = (unsigned char*)(w + 67108864);   // 16*256*1024  = 4 MB
  float*         eo   = (float*)(w + 71303168);           // 32768*256 f32 = 33554432 B
  int*           slot_token = (int*)(w + 104857600);      // 131072 B
  float*         slot_gate  = (float*)(w + 104988672);    // 131072 B
  TokenRec*      te         = (TokenRec*)(w + 105119744); // 262144 B
  unsigned int*  counts  = (unsigned int*)(w + 105381888);
  unsigned int*  cursor  = (unsigned int*)(w + 105381952);
  unsigned int*  offsets = (unsigned int*)(w + 105382016);
  int*           tok_slot = (int*)(w + 105382080);        // 131072 B
  // transient overlays on actA (dead before L1 GEMM writes actA)
  float*         sel_buf  = (float*)(w + 0);              // 1 MB
  float*         partials = (float*)(w + 1048576);        // 2 KB

  float* sel_out  = out + (size_t)S_TOK * D_OUT;
  float* loss_out = out + (size_t)S_TOK * D_OUT + (size_t)S_TOK * E_EXP;

  // fused + interleaved: convw (5 of 6 blocks) + router (1 of 6 blocks)
  k_router_convw<<<dim3(6144), dim3(256), 0, stream>>>(x, nois, Wr, sel_out, sel_buf, te,
                                                       W1, W2, W3, W4, Wt1, Wt2, Wt3, Wt4);

  k_stats<<<dim3(16), dim3(256), 0, stream>>>(sel_buf, te, partials);
  k_prefix_loss<<<dim3(1), dim3(64), 0, stream>>>(partials, counts, offsets, cursor, loss_out);
  k_listbuild<<<dim3(16), dim3(256), 0, stream>>>(te, offsets, cursor, slot_token, slot_gate, tok_slot);
  k_gather<<<dim3((2 * S_TOK * 64) / 256), dim3(256), 0, stream>>>(x, slot_token, actB);

  // Layer 1: [*,512] @ [512,500] -> relu -> actA (stride 512), 128x128 tiles
  k_gemm_mid<<<dim3(16, 4, E_EXP), dim3(256), 0, stream>>>(actB, Wt1, b1, actA, offsets, counts, 512, 512, H1D);
  // Layer 2: [*,500] @ [500,500] -> relu -> actB (stride 512)
  k_gemm_mid<<<dim3(16, 4, E_EXP), dim3(256), 0, stream>>>(actA, Wt2, b2, actB, offsets, counts, 512, 512, H2D);
  // Layer 3: [*,500] @ [500,1000] -> relu -> actA (stride 1024)
  k_gemm_mid<<<dim3(16, 8, E_EXP), dim3(256), 0, stream>>>(actB, Wt3, b3, actA, offsets, counts, 512, 1024, H3D);
  // Layer 4: [*,1000] @ [1000,256] -> eo[slot] = gate*(h3@W4+b4)   (128x64 tiles)
  k_gemm_fin<<<dim3(16, 4, E_EXP), dim3(256), 0, stream>>>(actA, Wt4, b4, eo, offsets, counts, slot_gate);
  // Combine: out[s] = eo[sl1] + eo[sl2]
  k_combine<<<dim3(S_TOK * 64 / 256), dim3(256), 0, stream>>>(eo, tok_slot, out);

  (void)in_sizes; (void)n_in; (void)out_size; (void)ws_size;
}

// Round 8
// 370.456 us; speedup vs baseline: 1.0450x; 1.0450x over previous
//
#include <hip/hip_runtime.h>
#include <stdint.h>

#define S_TOK 16384
#define M_DIM 512
#define E_EXP 16
#define D_OUT 256
#define H1D 500
#define H2D 500
#define H3D 1000

typedef float f32x4 __attribute__((ext_vector_type(4)));
typedef long lx2 __attribute__((ext_vector_type(2)));   // 16 B = two fp8 fragments
typedef int i32x2 __attribute__((ext_vector_type(2)));

template <bool HI>
__device__ __forceinline__ int pk8(float a, float b, int old) {
  return __builtin_amdgcn_cvt_pk_fp8_f32(a, b, old, HI);
}

// async global->LDS, 16B per lane; LDS dest = wave-uniform base + lane*16
__device__ __forceinline__ void ld_lds16(const unsigned char* g, unsigned char* l) {
  __builtin_amdgcn_global_load_lds(
      (const __attribute__((address_space(1))) unsigned int*)(const void*)g,
      (__attribute__((address_space(3))) unsigned int*)(void*)l, 16, 0, 0);
}

// fused waitcnt+barrier: nothing can slip between the count-wait and the barrier.
// Control flow is block-uniform at every call site.
__device__ __forceinline__ void barrier_vm4() { asm volatile("s_waitcnt vmcnt(4)\n\ts_barrier" ::: "memory"); }
__device__ __forceinline__ void barrier_vm3() { asm volatile("s_waitcnt vmcnt(3)\n\ts_barrier" ::: "memory"); }
__device__ __forceinline__ void barrier_vm0() { asm volatile("s_waitcnt vmcnt(0)\n\ts_barrier" ::: "memory"); }
__device__ __forceinline__ void barrier_lgkm0() { asm volatile("s_waitcnt lgkmcnt(0)\n\ts_barrier" ::: "memory"); }

struct TokenRec { int i1, i2; float g1, g2; };

// ---------------- FUSED router + weight-convert (independent workloads, one dispatch)
// blocks [0, 2560): convw PAIRS (2 tiles/block, all 8 global f32x4 loads issued
// up-front so tile-1's HBM latency hides under tile-0's transpose+store);
// blocks [2560, 3584): router (sequential layout -- the R5 arrangement).
// Router additionally accumulates expert counts + softmax-proxy sums via device
// atomics (LDS-reduced first), replacing the old stats/prefix kernels.
__global__ __launch_bounds__(256) void k_router_convw(const float* __restrict__ x,
                                                      const float* __restrict__ noise,
                                                      const float* __restrict__ Wr,
                                                      float* __restrict__ sel_out,
                                                      TokenRec* __restrict__ te,
                                                      const float* __restrict__ W1,
                                                      const float* __restrict__ W2,
                                                      const float* __restrict__ W3,
                                                      const float* __restrict__ W4,
                                                      unsigned char* __restrict__ D1,
                                                      unsigned char* __restrict__ D2,
                                                      unsigned char* __restrict__ D3,
                                                      unsigned char* __restrict__ D4,
                                                      unsigned int* __restrict__ countsTot,
                                                      float* __restrict__ proxyTot) {
  __shared__ float smem[8320];   // 33.3 KB: convw 2x tile[64][65] / router wr+reduce
  int t = threadIdx.x;

  if (blockIdx.x < 2560) {
    // ================= convw body: two tiles, pipelined =================
    int ry4 = t >> 4, cx4 = (t & 15) * 4;
    const float* sp[2]; unsigned char* dstp[2];
    int Kr[2], Nr[2], Kp[2], k0[2], n0[2];
#pragma unroll
    for (int p = 0; p < 2; p++) {
      int cid = blockIdx.x * 2 + p;
      int tb = cid % 320, e = cid / 320;
      const float* src; unsigned char* dst;
      int kr, nr, kp, np, kx, ny;
      if (tb < 64)        { src = W1; dst = D1; kr = 512;  nr = H1D; kp = 512;  np = 512;  kx = tb >> 3;  ny = tb & 7; }
      else if (tb < 128)  { tb -= 64;  src = W2; dst = D2; kr = H1D; nr = H2D; kp = 512;  np = 512;  kx = tb >> 3;  ny = tb & 7; }
      else if (tb < 256)  { tb -= 128; src = W3; dst = D3; kr = H2D; nr = H3D; kp = 512;  np = 1024; kx = tb >> 4;  ny = tb & 15; }
      else                { tb -= 256; src = W4; dst = D4; kr = H3D; nr = 256; kp = 1024; np = 256;  kx = tb >> 2;  ny = tb & 3; }
      sp[p] = src + (size_t)e * kr * nr;
      dstp[p] = dst + (size_t)e * np * kp;
      Kr[p] = kr; Nr[p] = nr; Kp[p] = kp; k0[p] = kx * 64; n0[p] = ny * 64;
    }
    // issue ALL 8 loads up-front (both tiles in flight)
    f32x4 va[2][4];
#pragma unroll
    for (int p = 0; p < 2; p++)
#pragma unroll
      for (int i = 0; i < 4; i++) {
        int k = k0[p] + ry4 + i * 16, n = n0[p] + cx4;
        f32x4 v;
        if (k < Kr[p] && n + 3 < Nr[p]) {
          v = *(const f32x4*)&sp[p][(size_t)k * Nr[p] + n];
        } else {
          v.x = (k < Kr[p] && n + 0 < Nr[p]) ? sp[p][(size_t)k * Nr[p] + n + 0] : 0.f;
          v.y = (k < Kr[p] && n + 1 < Nr[p]) ? sp[p][(size_t)k * Nr[p] + n + 1] : 0.f;
          v.z = (k < Kr[p] && n + 2 < Nr[p]) ? sp[p][(size_t)k * Nr[p] + n + 2] : 0.f;
          v.w = (k < Kr[p] && n + 3 < Nr[p]) ? sp[p][(size_t)k * Nr[p] + n + 3] : 0.f;
        }
        va[p][i] = v;
      }
    int nl = t >> 2, q = t & 3;
#pragma unroll
    for (int p = 0; p < 2; p++) {
      float* tile = smem + p * 4160;   // [64][65]
#pragma unroll
      for (int i = 0; i < 4; i++) {
        int r = ry4 + i * 16;
        tile[r * 65 + cx4 + 0] = va[p][i].x; tile[r * 65 + cx4 + 1] = va[p][i].y;
        tile[r * 65 + cx4 + 2] = va[p][i].z; tile[r * 65 + cx4 + 3] = va[p][i].w;
      }
      __syncthreads();
      int b0 = pk8<false>(tile[(q * 8 + 0) * 65 + nl], tile[(q * 8 + 1) * 65 + nl], 0);
      b0 = pk8<true>(tile[(q * 8 + 2) * 65 + nl], tile[(q * 8 + 3) * 65 + nl], b0);
      int b1 = pk8<false>(tile[(q * 8 + 4) * 65 + nl], tile[(q * 8 + 5) * 65 + nl], 0);
      b1 = pk8<true>(tile[(q * 8 + 6) * 65 + nl], tile[(q * 8 + 7) * 65 + nl], b1);
      int c0 = pk8<false>(tile[(32 + q * 8 + 0) * 65 + nl], tile[(32 + q * 8 + 1) * 65 + nl], 0);
      c0 = pk8<true>(tile[(32 + q * 8 + 2) * 65 + nl], tile[(32 + q * 8 + 3) * 65 + nl], c0);
      int c1 = pk8<false>(tile[(32 + q * 8 + 4) * 65 + nl], tile[(32 + q * 8 + 5) * 65 + nl], 0);
      c1 = pk8<true>(tile[(32 + q * 8 + 6) * 65 + nl], tile[(32 + q * 8 + 7) * 65 + nl], c1);
      uint4 pk; pk.x = (unsigned)b0; pk.y = (unsigned)b1; pk.z = (unsigned)c0; pk.w = (unsigned)c1;
      *(uint4*)&dstp[p][(size_t)(n0[p] + nl) * Kp[p] + k0[p] + q * 16] = pk;
    }
    return;
  }

  // ================= router body =================
  float* wr = smem;                          // 16*516 floats
  float* pr_lds = smem + 8256;               // 16 floats
  unsigned int* hist_lds = (unsigned int*)(smem + 8272);  // 16 uints
  int rb = blockIdx.x - 2560;
  for (int i = t; i < E_EXP * M_DIM; i += 256) {
    int e = i >> 9, m = i & 511;
    wr[e * 516 + m] = Wr[i];
  }
  if (t < E_EXP) { pr_lds[t] = 0.f; hist_lds[t] = 0u; }
  __syncthreads();

  int wv = t >> 6, l = t & 63;
  int e = l & 15, tg = l >> 4;
  int s = rb * 16 + wv * 4 + tg;

  const float* xr = x + (size_t)s * M_DIM;
  const float* wre = &wr[e * 516];
  double a0 = 0.0, a1 = 0.0, a2 = 0.0, a3 = 0.0;
#pragma unroll 4
  for (int m = 0; m < M_DIM; m += 4) {
    f32x4 xv = *(const f32x4*)(xr + m);
    f32x4 wv4 = *(const f32x4*)(wre + m);
    a0 += (double)xv.x * (double)wv4.x;
    a1 += (double)xv.y * (double)wv4.y;
    a2 += (double)xv.z * (double)wv4.z;
    a3 += (double)xv.w * (double)wv4.w;
  }
  double a = (a0 + a1) + (a2 + a3);
  a += (double)noise[(size_t)s * E_EXP + e];

  double mx = a;
#pragma unroll
  for (int off = 8; off >= 1; off >>= 1) { double o = __shfl_xor(mx, off, 64); mx = (o > mx) ? o : mx; }
  double p = exp(a - mx);
  double sum = p;
#pragma unroll
  for (int off = 8; off >= 1; off >>= 1) sum += __shfl_xor(sum, off, 64);
  float spr = (float)(p / sum);
  atomicAdd(&pr_lds[e], spr);   // proxy partial (replaces sel_buf + stats)

  unsigned long long pb = __double_as_longlong(p);
  unsigned long long key = (pb & ~0xFFull) | (unsigned long long)(255 - e);
  unsigned long long k1 = key;
#pragma unroll
  for (int off = 8; off >= 1; off >>= 1) { unsigned long long o = __shfl_xor(k1, off, 64); k1 = (o > k1) ? o : k1; }
  int i1 = 255 - (int)(k1 & 0xFFull);
  unsigned long long key2 = (e == i1) ? 0ull : key;
  unsigned long long k2 = key2;
#pragma unroll
  for (int off = 8; off >= 1; off >>= 1) { unsigned long long o = __shfl_xor(k2, off, 64); k2 = (o > k2) ? o : k2; }
  int i2 = 255 - (int)(k2 & 0xFFull);

  double p1 = __shfl(p, tg * 16 + i1, 64);
  double p2 = __shfl(p, tg * 16 + i2, 64);

  sel_out[(size_t)s * E_EXP + e] = (e == i1 || e == i2) ? 1.f : 0.f;
  if (e == 0) {
    double inv = 1.0 / (p1 + p2);
    TokenRec r; r.i1 = i1; r.i2 = i2; r.g1 = (float)(p1 * inv); r.g2 = (float)(p2 * inv);
    te[s] = r;
    atomicAdd(&hist_lds[i1], 1u);
    atomicAdd(&hist_lds[i2], 1u);
  }
  __syncthreads();
  if (t < E_EXP) {
    atomicAdd(&countsTot[t], hist_lds[t]);
    atomicAdd(&proxyTot[t], pr_lds[t]);
  }
}

// ---------------- dispatch: per-block independent prefix + slot build + loss -------
// Replaces stats + prefix_loss + listbuild with ONE kernel, no cross-block comms:
// block b re-histograms te[0, b*1024) (L2-hot, <=240 KB) for its own lbase.
__global__ __launch_bounds__(256) void k_dispatch(const TokenRec* __restrict__ te,
                                                  const unsigned int* __restrict__ countsTot,
                                                  const float* __restrict__ proxyTot,
                                                  unsigned int* __restrict__ offsets_g,
                                                  int* __restrict__ slot_token,
                                                  float* __restrict__ slot_gate,
                                                  int* __restrict__ tok_slot,
                                                  float* __restrict__ out_loss) {
  __shared__ unsigned int histb[E_EXP], lbase[E_EXP], lcur[E_EXP];
  int t = threadIdx.x, b = blockIdx.x;
  int base = b * 1024;
  if (t < E_EXP) { histb[t] = 0u; lcur[t] = 0u; }
  __syncthreads();
  for (int i = t; i < base; i += 256) {
    TokenRec r = te[i];
    atomicAdd(&histb[r.i1], 1u);
    atomicAdd(&histb[r.i2], 1u);
  }
  __syncthreads();
  if (t < E_EXP) {
    unsigned int off = 0;
    for (int e = 0; e < t; e++) off += countsTot[e];
    lbase[t] = off + histb[t];
    if (b == 0) offsets_g[t] = off;
  }
  if (b == 0 && t == 16) {
    float ls = 0.f;
    for (int e = 0; e < E_EXP; e++) ls += proxyTot[e] * (float)countsTot[e];
    out_loss[0] = ls * ((float)E_EXP / ((float)S_TOK * (float)S_TOK));
    out_loss[1] = 0.f;
  }
  __syncthreads();
  for (int i = t; i < 1024; i += 256) {
    int s = base + i;
    TokenRec r = te[s];
    unsigned int p1 = atomicAdd(&lcur[r.i1], 1u);
    int sl1 = (int)(lbase[r.i1] + p1);
    slot_token[sl1] = s; slot_gate[sl1] = r.g1;
    unsigned int p2 = atomicAdd(&lcur[r.i2], 1u);
    int sl2 = (int)(lbase[r.i2] + p2);
    slot_token[sl2] = s; slot_gate[sl2] = r.g2;
    tok_slot[2 * s] = sl1;
    tok_slot[2 * s + 1] = sl2;
  }
}

// ---------------- gather x rows -> fp8 compact activations (k-interleaved) ----------
// within each 64-k block: byte = q*16 + h*8 + j  <->  k = h*32 + q*8 + j
__global__ __launch_bounds__(256) void k_gather(const float* __restrict__ x,
                                                const int* __restrict__ slot_token,
                                                unsigned char* __restrict__ xg) {
  int idx = blockIdx.x * 256 + threadIdx.x;   // 32768 * 64
  int row = idx >> 6, t6 = idx & 63;
  int blk = t6 >> 3, q = (t6 >> 1) & 3, h = t6 & 1;
  int tkn = slot_token[row];
  const float* xp = x + (size_t)tkn * M_DIM + blk * 64 + h * 32 + q * 8;
  f32x4 v0 = *(const f32x4*)xp;
  f32x4 v1 = *(const f32x4*)(xp + 4);
  int b0 = pk8<false>(v0.x, v0.y, 0); b0 = pk8<true>(v0.z, v0.w, b0);
  int b1 = pk8<false>(v1.x, v1.y, 0); b1 = pk8<true>(v1.z, v1.w, b1);
  i32x2 o; o.x = b0; o.y = b1;
  *(i32x2*)&xg[(size_t)row * 512 + blk * 64 + q * 16 + h * 8] = o;
}

// ---------------- grouped GEMM (fp8, BK=64): 128x128 tile, async dbuf staging,
// XOR-swizzled 16-B segments (0 conflicts). SWAPPED operands: A=weights, B=acts.
// T4 counted-vmcnt schedule. EPILOGUE VIA LDS -> coalesced dwordx4 stores.
// mid: out = relu(in @ W^T + b) -> fp8 (pad cols zeroed)
__global__ __launch_bounds__(256, 3) void k_gemm_mid(const unsigned char* __restrict__ in,
                                                  const unsigned char* __restrict__ wt,
                                                  const float* __restrict__ bias,
                                                  unsigned char* __restrict__ out,
                                                  const unsigned int* __restrict__ offsets,
                                                  const unsigned int* __restrict__ counts,
                                                  int KP, int NP, int NREAL) {
  int e = blockIdx.z;
  int n_e = (int)counts[e];
  if (n_e == 0) return;
  int base = (int)offsets[e];
  int bn = blockIdx.y;
  __shared__ __align__(16) unsigned char As[2][128 * 64];  // 2 x 8 KB activations (+ epilogue tile)
  __shared__ __align__(16) unsigned char Bs[2][128 * 64];  // 2 x 8 KB weights
  int t = threadIdx.x;
  int w = t >> 6, l = t & 63;
  int wm = w & 1, wn = w >> 1;
  int lr = l & 15, lq = l >> 4;
  int r_ = l >> 2, s_ = l & 3;
  int s2 = s_ ^ ((r_ >> 1) & 3);               // swizzled source segment (16 B units)
  int rsw = (lq ^ ((lr >> 1) & 3)) * 16;       // read-side swizzled byte offset
  int c0 = 2 * w, c1 = 2 * w + 1;              // two 16-row chunks per wave

  unsigned char* dA0[2] = {&As[0][c0 * 1024], &As[1][c0 * 1024]};
  unsigned char* dA1[2] = {&As[0][c1 * 1024], &As[1][c1 * 1024]};
  unsigned char* dB0[2] = {&Bs[0][c0 * 1024], &Bs[1][c0 * 1024]};
  unsigned char* dB1[2] = {&Bs[0][c1 * 1024], &Bs[1][c1 * 1024]};

  const unsigned char* bW = wt + (size_t)e * NP * KP;
  const unsigned char* bs0 = bW + (size_t)(bn * 128 + c0 * 16 + r_) * KP + s2 * 16;
  const unsigned char* bs1 = bW + (size_t)(bn * 128 + c1 * 16 + r_) * KP + s2 * 16;
  int nk = KP >> 6;

  for (int bm = blockIdx.x; bm * 128 < n_e; bm += gridDim.x) {
    int ra = bm * 128 + c0 * 16 + r_; ra = (ra < n_e) ? ra : (n_e - 1);
    int rb = bm * 128 + c1 * 16 + r_; rb = (rb < n_e) ? rb : (n_e - 1);
    const unsigned char* a0 = in + (size_t)(base + ra) * KP + s2 * 16;
    const unsigned char* a1 = in + (size_t)(base + rb) * KP + s2 * 16;
    const unsigned char* b0 = bs0;
    const unsigned char* b1 = bs1;
    f32x4 acc[4][4];
#pragma unroll
    for (int i = 0; i < 4; i++)
#pragma unroll
      for (int j = 0; j < 4; j++) acc[i][j] = (f32x4){0.f, 0.f, 0.f, 0.f};

    // prologue: stage buf0 (4 loads in flight)
    ld_lds16(a0, dA0[0]); ld_lds16(a1, dA1[0]); ld_lds16(b0, dB0[0]); ld_lds16(b1, dB1[0]);
    a0 += 64; a1 += 64; b0 += 64; b1 += 64;

    for (int ks = 0; ks < nk; ks++) {
      int cb = ks & 1, nb = cb ^ 1;
      // stage next K-tile FIRST, then wait only for the previous 4 (buf[cb]).
      if (ks + 1 < nk) {
        ld_lds16(a0, dA0[nb]); ld_lds16(a1, dA1[nb]); ld_lds16(b0, dB0[nb]); ld_lds16(b1, dB1[nb]);
        a0 += 64; a1 += 64; b0 += 64; b1 += 64;
        barrier_vm4();
      } else {
        barrier_vm0();
      }
      lx2 af[4], wf[4];
#pragma unroll
      for (int mi = 0; mi < 4; mi++) af[mi] = *(const lx2*)&As[cb][(wm * 64 + mi * 16 + lr) * 64 + rsw];
#pragma unroll
      for (int ni = 0; ni < 4; ni++) wf[ni] = *(const lx2*)&Bs[cb][(wn * 64 + ni * 16 + lr) * 64 + rsw];
      __builtin_amdgcn_s_setprio(1);
#pragma unroll
      for (int ni = 0; ni < 4; ni++)
#pragma unroll
        for (int mi = 0; mi < 4; mi++) {
          acc[ni][mi] = __builtin_amdgcn_mfma_f32_16x16x32_fp8_fp8(wf[ni].x, af[mi].x, acc[ni][mi], 0, 0, 0);
          acc[ni][mi] = __builtin_amdgcn_mfma_f32_16x16x32_fp8_fp8(wf[ni].y, af[mi].y, acc[ni][mi], 0, 0, 0);
        }
      __builtin_amdgcn_s_setprio(0);
      barrier_lgkm0();
    }

    // ---- epilogue via LDS: pack quads -> swizzled LDS tile -> coalesced 16B stores
    unsigned char* eb = &As[0][0];   // 16 KB: [row 0..127][byte 0..127]
#pragma unroll
    for (int ni = 0; ni < 4; ni++) {
      int nl = wn * 64 + ni * 16 + lq * 4;       // local col (0..127), 4-aligned
      int n0 = bn * 128 + nl;                    // global col
      bool cok = n0 < NREAL;                     // NREAL % 4 == 0 -> whole quad in/out
      f32x4 bv = (f32x4){0.f, 0.f, 0.f, 0.f};
      if (cok) bv = *(const f32x4*)&bias[(size_t)e * NREAL + n0];
      int k6 = nl & 63;
      int off = ((nl >> 6) << 6) + ((k6 >> 3) & 3) * 16 + ((k6 >> 5) & 1) * 8 + (k6 & 7);
#pragma unroll
      for (int mi = 0; mi < 4; mi++) {
        int row = wm * 64 + mi * 16 + lr;        // local row 0..127
        unsigned int pkv = 0u;
        if (cok) {
          f32x4 v = acc[ni][mi];
          int p = pk8<false>(fmaxf(v.x + bv.x, 0.f), fmaxf(v.y + bv.y, 0.f), 0);
          p = pk8<true>(fmaxf(v.z + bv.z, 0.f), fmaxf(v.w + bv.w, 0.f), p);
          pkv = (unsigned int)p;
        }
        *(unsigned int*)&eb[row * 128 + (off ^ ((row & 7) << 4))] = pkv;
      }
    }
    barrier_lgkm0();   // tile complete in LDS
#pragma unroll
    for (int it = 0; it < 4; it++) {
      int idx = it * 256 + t;
      int row = idx >> 3, seg = idx & 7;
      uint4 val = *(const uint4*)&eb[row * 128 + ((seg * 16) ^ ((row & 7) << 4))];
      int m = bm * 128 + row;
      if (m < n_e)
        *(uint4*)&out[(size_t)(base + m) * NP + bn * 128 + seg * 16] = val;
    }
    __syncthreads();   // epilogue LDS reads done before next tile's staging overwrites As
  }
}

// fin: 128x64 tile, swapped operands; eo[slot] = gate * (h3 @ W4 + b4);
// each thread stores float4 (4 consecutive cols of one row). T4+T5 schedule.
__global__ __launch_bounds__(256, 4) void k_gemm_fin(const unsigned char* __restrict__ in,
                                                  const unsigned char* __restrict__ wt,
                                                  const float* __restrict__ bias,
                                                  float* __restrict__ eo,
                                                  const unsigned int* __restrict__ offsets,
                                                  const unsigned int* __restrict__ counts,
                                                  const float* __restrict__ slot_gate) {
  const int KP = 1024, NP = 256;
  int e = blockIdx.z;
  int n_e = (int)counts[e];
  if (n_e == 0) return;
  int base = (int)offsets[e];
  int bn = blockIdx.y;
  __shared__ __align__(16) unsigned char As[2][128 * 64];  // 2 x 8 KB activations
  __shared__ __align__(16) unsigned char Bs[2][64 * 64];   // 2 x 4 KB weights
  int t = threadIdx.x;
  int w = t >> 6, l = t & 63;
  int wm = w & 1, wn = w >> 1;
  int lr = l & 15, lq = l >> 4;
  int r_ = l >> 2, s_ = l & 3;
  int s2 = s_ ^ ((r_ >> 1) & 3);
  int rsw = (lq ^ ((lr >> 1) & 3)) * 16;
  int c0 = 2 * w, c1 = 2 * w + 1;

  unsigned char* dA0[2] = {&As[0][c0 * 1024], &As[1][c0 * 1024]};
  unsigned char* dA1[2] = {&As[0][c1 * 1024], &As[1][c1 * 1024]};
  unsigned char* dB[2]  = {&Bs[0][w * 1024], &Bs[1][w * 1024]};

  const unsigned char* bW = wt + (size_t)e * NP * KP;
  const unsigned char* bsrc = bW + (size_t)(bn * 64 + w * 16 + r_) * KP + s2 * 16;
  int nk = KP >> 6;

  for (int bm = blockIdx.x; bm * 128 < n_e; bm += gridDim.x) {
    int ra = bm * 128 + c0 * 16 + r_; ra = (ra < n_e) ? ra : (n_e - 1);
    int rb = bm * 128 + c1 * 16 + r_; rb = (rb < n_e) ? rb : (n_e - 1);
    const unsigned char* a0 = in + (size_t)(base + ra) * KP + s2 * 16;
    const unsigned char* a1 = in + (size_t)(base + rb) * KP + s2 * 16;
    const unsigned char* bq = bsrc;
    f32x4 acc[2][4];
#pragma unroll
    for (int i = 0; i < 2; i++)
#pragma unroll
      for (int j = 0; j < 4; j++) acc[i][j] = (f32x4){0.f, 0.f, 0.f, 0.f};

    ld_lds16(a0, dA0[0]); ld_lds16(a1, dA1[0]); ld_lds16(bq, dB[0]);
    a0 += 64; a1 += 64; bq += 64;

    for (int ks = 0; ks < nk; ks++) {
      int cb = ks & 1, nb = cb ^ 1;
      if (ks + 1 < nk) {
        ld_lds16(a0, dA0[nb]); ld_lds16(a1, dA1[nb]); ld_lds16(bq, dB[nb]);
        a0 += 64; a1 += 64; bq += 64;
        barrier_vm3();
      } else {
        barrier_vm0();
      }
      lx2 af[4], wf[2];
#pragma unroll
      for (int mi = 0; mi < 4; mi++) af[mi] = *(const lx2*)&As[cb][(wm * 64 + mi * 16 + lr) * 64 + rsw];
#pragma unroll
      for (int ni = 0; ni < 2; ni++) wf[ni] = *(const lx2*)&Bs[cb][(wn * 32 + ni * 16 + lr) * 64 + rsw];
      __builtin_amdgcn_s_setprio(1);
#pragma unroll
      for (int ni = 0; ni < 2; ni++)
#pragma unroll
        for (int mi = 0; mi < 4; mi++) {
          acc[ni][mi] = __builtin_amdgcn_mfma_f32_16x16x32_fp8_fp8(wf[ni].x, af[mi].x, acc[ni][mi], 0, 0, 0);
          acc[ni][mi] = __builtin_amdgcn_mfma_f32_16x16x32_fp8_fp8(wf[ni].y, af[mi].y, acc[ni][mi], 0, 0, 0);
        }
      __builtin_amdgcn_s_setprio(0);
      barrier_lgkm0();
    }

    int mbase = bm * 128 + wm * 64;
    int nbase = bn * 64 + wn * 32;
#pragma unroll
    for (int ni = 0; ni < 2; ni++) {
      int n0 = nbase + ni * 16 + lq * 4;
      f32x4 bv = *(const f32x4*)&bias[(size_t)e * 256 + n0];
#pragma unroll
      for (int mi = 0; mi < 4; mi++) {
        int m = mbase + mi * 16 + lr;
        if (m < n_e) {
          int gr = base + m;
          float g = slot_gate[gr];
          f32x4 v;
          v.x = g * (acc[ni][mi].x + bv.x);
          v.y = g * (acc[ni][mi].y + bv.y);
          v.z = g * (acc[ni][mi].z + bv.z);
          v.w = g * (acc[ni][mi].w + bv.w);
          *(f32x4*)&eo[(size_t)gr * NP + n0] = v;
        }
      }
    }
  }
}

// ---------------- combine: out[s] = eo[sl1(s)] + eo[sl2(s)] ----------------
__global__ __launch_bounds__(256) void k_combine(const float* __restrict__ eo,
                                                 const int* __restrict__ tok_slot,
                                                 float* __restrict__ out) {
  int idx = blockIdx.x * 256 + threadIdx.x;
  int s = idx >> 6, q = idx & 63;
  int sl1 = tok_slot[2 * s], sl2 = tok_slot[2 * s + 1];
  f32x4 v1 = *(const f32x4*)&eo[(size_t)sl1 * D_OUT + q * 4];
  f32x4 v2 = *(const f32x4*)&eo[(size_t)sl2 * D_OUT + q * 4];
  *(f32x4*)&out[(size_t)s * D_OUT + q * 4] = v1 + v2;
}

extern "C" void kernel_launch(void* const* d_in, const int* in_sizes, int n_in,
                              void* d_out, int out_size, void* d_ws, size_t ws_size,
                              hipStream_t stream) {
  const float* x    = (const float*)d_in[0];
  const float* nois = (const float*)d_in[1];
  const float* Wr   = (const float*)d_in[2];
  const float* W1   = (const float*)d_in[3];
  const float* b1   = (const float*)d_in[4];
  const float* W2   = (const float*)d_in[5];
  const float* b2   = (const float*)d_in[6];
  const float* W3   = (const float*)d_in[7];
  const float* b3   = (const float*)d_in[8];
  const float* W4   = (const float*)d_in[9];
  const float* b4   = (const float*)d_in[10];
  float* out = (float*)d_out;

  char* w = (char*)d_ws;
  unsigned char* actA = (unsigned char*)(w + 0);          // 32768*1024 fp8 = 33554432 B
  unsigned char* actB = (unsigned char*)(w + 33554432);   // 32768*512 fp8  = 16777216 B
  unsigned char* Wt1  = (unsigned char*)(w + 50331648);   // 16*512*512   = 4 MB
  unsigned char* Wt2  = (unsigned char*)(w + 54525952);   // 4 MB
  unsigned char* Wt3  = (unsigned char*)(w + 58720256);   // 16*1024*512  = 8 MB
  unsigned char* Wt4  = (unsigned char*)(w + 67108864);   // 16*256*1024  = 4 MB
  float*         eo   = (float*)(w + 71303168);           // 32768*256 f32 = 33554432 B
  int*           slot_token = (int*)(w + 104857600);      // 131072 B
  float*         slot_gate  = (float*)(w + 104988672);    // 131072 B
  TokenRec*      te         = (TokenRec*)(w + 105119744); // 262144 B
  unsigned int*  countsTot = (unsigned int*)(w + 105381888);  // 64 B (atomic)
  float*         proxyTot  = (float*)(w + 105381952);         // 64 B (atomic)
  unsigned int*  offsets = (unsigned int*)(w + 105382016);
  int*           tok_slot = (int*)(w + 105382080);        // 131072 B

  float* sel_out  = out + (size_t)S_TOK * D_OUT;
  float* loss_out = out + (size_t)S_TOK * D_OUT + (size_t)S_TOK * E_EXP;

  // zero the atomic accumulators (graph-capture-safe async memset)
  hipMemsetAsync(w + 105381888, 0, 128, stream);

  // fused: convw pairs (blocks 0..2559) + router (blocks 2560..3583)
  k_router_convw<<<dim3(3584), dim3(256), 0, stream>>>(x, nois, Wr, sel_out, te,
                                                       W1, W2, W3, W4, Wt1, Wt2, Wt3, Wt4,
                                                       countsTot, proxyTot);

  // dispatch: replaces stats + prefix_loss + listbuild
  k_dispatch<<<dim3(16), dim3(256), 0, stream>>>(te, countsTot, proxyTot, offsets,
                                                 slot_token, slot_gate, tok_slot, loss_out);

  k_gather<<<dim3((2 * S_TOK * 64) / 256), dim3(256), 0, stream>>>(x, slot_token, actB);

  // Layer 1: [*,512] @ [512,500] -> relu -> actA (stride 512), 128x128 tiles
  k_gemm_mid<<<dim3(16, 4, E_EXP), dim3(256), 0, stream>>>(actB, Wt1, b1, actA, offsets, countsTot, 512, 512, H1D);
  // Layer 2: [*,500] @ [500,500] -> relu -> actB (stride 512)
  k_gemm_mid<<<dim3(16, 4, E_EXP), dim3(256), 0, stream>>>(actA, Wt2, b2, actB, offsets, countsTot, 512, 512, H2D);
  // Layer 3: [*,500] @ [500,1000] -> relu -> actA (stride 1024)
  k_gemm_mid<<<dim3(16, 8, E_EXP), dim3(256), 0, stream>>>(actB, Wt3, b3, actA, offsets, countsTot, 512, 1024, H3D);
  // Layer 4: [*,1000] @ [1000,256] -> eo[slot] = gate*(h3@W4+b4)   (128x64 tiles)
  k_gemm_fin<<<dim3(16, 4, E_EXP), dim3(256), 0, stream>>>(actA, Wt4, b4, eo, offsets, countsTot, slot_gate);
  // Combine: out[s] = eo[sl1] + eo[sl2]
  k_combine<<<dim3(S_TOK * 64 / 256), dim3(256), 0, stream>>>(eo, tok_slot, out);

  (void)in_sizes; (void)n_in; (void)out_size; (void)ws_size;
}

// Round 9
// 369.287 us; speedup vs baseline: 1.0483x; 1.0032x over previous
//
#include <hip/hip_runtime.h>
#include <stdint.h>

#define S_TOK 16384
#define M_DIM 512
#define E_EXP 16
#define D_OUT 256
#define H1D 500
#define H2D 500
#define H3D 1000

typedef float f32x4 __attribute__((ext_vector_type(4)));
typedef long lx2 __attribute__((ext_vector_type(2)));   // 16 B = two fp8 fragments
typedef int i32x2 __attribute__((ext_vector_type(2)));

template <bool HI>
__device__ __forceinline__ int pk8(float a, float b, int old) {
  return __builtin_amdgcn_cvt_pk_fp8_f32(a, b, old, HI);
}

// async global->LDS, 16B per lane; LDS dest = wave-uniform base + lane*16
__device__ __forceinline__ void ld_lds16(const unsigned char* g, unsigned char* l) {
  __builtin_amdgcn_global_load_lds(
      (const __attribute__((address_space(1))) unsigned int*)(const void*)g,
      (__attribute__((address_space(3))) unsigned int*)(void*)l, 16, 0, 0);
}

// fused waitcnt+barrier: nothing can slip between the count-wait and the barrier.
// Control flow is block-uniform at every call site.
__device__ __forceinline__ void barrier_vm4() { asm volatile("s_waitcnt vmcnt(4)\n\ts_barrier" ::: "memory"); }
__device__ __forceinline__ void barrier_vm3() { asm volatile("s_waitcnt vmcnt(3)\n\ts_barrier" ::: "memory"); }
__device__ __forceinline__ void barrier_vm0() { asm volatile("s_waitcnt vmcnt(0)\n\ts_barrier" ::: "memory"); }
__device__ __forceinline__ void barrier_lgkm0() { asm volatile("s_waitcnt lgkmcnt(0)\n\ts_barrier" ::: "memory"); }

struct TokenRec { int i1, i2; float g1, g2; };

// ---------------- FUSED router + weight-convert (independent workloads, one dispatch)
// R5 layout (measured fastest): blocks [0, 5120) = convw, [5120, 6144) = router.
// convw: the 4 f32x4 loads are issued into REGISTERS up-front (block-uniform
// full-tile branch keeps the common case branch-free) so the HBM round-trips
// overlap, instead of the load->LDS-store serial chain of the old body.
// Router accumulates expert counts + softmax-proxy sums via device atomics.
__global__ __launch_bounds__(256) void k_router_convw(const float* __restrict__ x,
                                                      const float* __restrict__ noise,
                                                      const float* __restrict__ Wr,
                                                      float* __restrict__ sel_out,
                                                      TokenRec* __restrict__ te,
                                                      const float* __restrict__ W1,
                                                      const float* __restrict__ W2,
                                                      const float* __restrict__ W3,
                                                      const float* __restrict__ W4,
                                                      unsigned char* __restrict__ D1,
                                                      unsigned char* __restrict__ D2,
                                                      unsigned char* __restrict__ D3,
                                                      unsigned char* __restrict__ D4,
                                                      unsigned int* __restrict__ countsTot,
                                                      float* __restrict__ proxyTot) {
  __shared__ float smem[8320];   // 33.3 KB: convw tile[64][65] / router wr + reduce
  int t = threadIdx.x;

  if (blockIdx.x < 5120) {
    // ================= convw body =================
    float (*tile)[65] = (float(*)[65])smem;   // tile[k_local][n_local], pad 65
    int cid = blockIdx.x;
    int tb = cid % 320, e = cid / 320;
    const float* src; unsigned char* dst;
    int Kr, Nr, Kp, Np, kx, ny;
    if (tb < 64)        { src = W1; dst = D1; Kr = 512;  Nr = H1D; Kp = 512;  Np = 512;  kx = tb >> 3;  ny = tb & 7; }
    else if (tb < 128)  { tb -= 64;  src = W2; dst = D2; Kr = H1D; Nr = H2D; Kp = 512;  Np = 512;  kx = tb >> 3;  ny = tb & 7; }
    else if (tb < 256)  { tb -= 128; src = W3; dst = D3; Kr = H2D; Nr = H3D; Kp = 512;  Np = 1024; kx = tb >> 4;  ny = tb & 15; }
    else                { tb -= 256; src = W4; dst = D4; Kr = H3D; Nr = 256; Kp = 1024; Np = 256;  kx = tb >> 2;  ny = tb & 3; }
    int k0 = kx * 64, n0 = ny * 64;
    const float* sp = src + (size_t)e * Kr * Nr;
    int ry4 = t >> 4, cx4 = (t & 15) * 4;

    // ---- issue all 4 loads up-front into registers (independent, in flight together)
    f32x4 va[4];
    bool full = (k0 + 63 < Kr) && (n0 + 63 < Nr);   // block-uniform branch
    if (full) {
#pragma unroll
      for (int i = 0; i < 4; i++)
        va[i] = *(const f32x4*)&sp[(size_t)(k0 + ry4 + i * 16) * Nr + n0 + cx4];
    } else {
#pragma unroll
      for (int i = 0; i < 4; i++) {
        int k = k0 + ry4 + i * 16, n = n0 + cx4;
        f32x4 v;
        if (k < Kr && n + 3 < Nr) {
          v = *(const f32x4*)&sp[(size_t)k * Nr + n];
        } else {
          v.x = (k < Kr && n + 0 < Nr) ? sp[(size_t)k * Nr + n + 0] : 0.f;
          v.y = (k < Kr && n + 1 < Nr) ? sp[(size_t)k * Nr + n + 1] : 0.f;
          v.z = (k < Kr && n + 2 < Nr) ? sp[(size_t)k * Nr + n + 2] : 0.f;
          v.w = (k < Kr && n + 3 < Nr) ? sp[(size_t)k * Nr + n + 3] : 0.f;
        }
        va[i] = v;
      }
    }
    // ---- LDS transpose staging (after all loads issued)
#pragma unroll
    for (int i = 0; i < 4; i++) {
      int r = ry4 + i * 16;
      tile[r][cx4 + 0] = va[i].x; tile[r][cx4 + 1] = va[i].y;
      tile[r][cx4 + 2] = va[i].z; tile[r][cx4 + 3] = va[i].w;
    }
    __syncthreads();
    int nl = t >> 2, q = t & 3;
    int b0 = pk8<false>(tile[q * 8 + 0][nl], tile[q * 8 + 1][nl], 0);
    b0 = pk8<true>(tile[q * 8 + 2][nl], tile[q * 8 + 3][nl], b0);
    int b1 = pk8<false>(tile[q * 8 + 4][nl], tile[q * 8 + 5][nl], 0);
    b1 = pk8<true>(tile[q * 8 + 6][nl], tile[q * 8 + 7][nl], b1);
    int c0 = pk8<false>(tile[32 + q * 8 + 0][nl], tile[32 + q * 8 + 1][nl], 0);
    c0 = pk8<true>(tile[32 + q * 8 + 2][nl], tile[32 + q * 8 + 3][nl], c0);
    int c1 = pk8<false>(tile[32 + q * 8 + 4][nl], tile[32 + q * 8 + 5][nl], 0);
    c1 = pk8<true>(tile[32 + q * 8 + 6][nl], tile[32 + q * 8 + 7][nl], c1);
    uint4 pk; pk.x = (unsigned)b0; pk.y = (unsigned)b1; pk.z = (unsigned)c0; pk.w = (unsigned)c1;
    *(uint4*)&dst[(size_t)e * Np * Kp + (size_t)(n0 + nl) * Kp + k0 + q * 16] = pk;
    return;
  }

  // ================= router body =================
  float* wr = smem;                          // 16*516 floats
  float* pr_lds = smem + 8256;               // 16 floats
  unsigned int* hist_lds = (unsigned int*)(smem + 8272);  // 16 uints
  int rb = blockIdx.x - 5120;
  for (int i = t; i < E_EXP * M_DIM; i += 256) {
    int e = i >> 9, m = i & 511;
    wr[e * 516 + m] = Wr[i];
  }
  if (t < E_EXP) { pr_lds[t] = 0.f; hist_lds[t] = 0u; }
  __syncthreads();

  int wv = t >> 6, l = t & 63;
  int e = l & 15, tg = l >> 4;
  int s = rb * 16 + wv * 4 + tg;

  const float* xr = x + (size_t)s * M_DIM;
  const float* wre = &wr[e * 516];
  double a0 = 0.0, a1 = 0.0, a2 = 0.0, a3 = 0.0;
#pragma unroll 4
  for (int m = 0; m < M_DIM; m += 4) {
    f32x4 xv = *(const f32x4*)(xr + m);
    f32x4 wv4 = *(const f32x4*)(wre + m);
    a0 += (double)xv.x * (double)wv4.x;
    a1 += (double)xv.y * (double)wv4.y;
    a2 += (double)xv.z * (double)wv4.z;
    a3 += (double)xv.w * (double)wv4.w;
  }
  double a = (a0 + a1) + (a2 + a3);
  a += (double)noise[(size_t)s * E_EXP + e];

  double mx = a;
#pragma unroll
  for (int off = 8; off >= 1; off >>= 1) { double o = __shfl_xor(mx, off, 64); mx = (o > mx) ? o : mx; }
  double p = exp(a - mx);
  double sum = p;
#pragma unroll
  for (int off = 8; off >= 1; off >>= 1) sum += __shfl_xor(sum, off, 64);
  float spr = (float)(p / sum);
  atomicAdd(&pr_lds[e], spr);   // proxy partial (replaces sel_buf + stats)

  unsigned long long pb = __double_as_longlong(p);
  unsigned long long key = (pb & ~0xFFull) | (unsigned long long)(255 - e);
  unsigned long long k1 = key;
#pragma unroll
  for (int off = 8; off >= 1; off >>= 1) { unsigned long long o = __shfl_xor(k1, off, 64); k1 = (o > k1) ? o : k1; }
  int i1 = 255 - (int)(k1 & 0xFFull);
  unsigned long long key2 = (e == i1) ? 0ull : key;
  unsigned long long k2 = key2;
#pragma unroll
  for (int off = 8; off >= 1; off >>= 1) { unsigned long long o = __shfl_xor(k2, off, 64); k2 = (o > k2) ? o : k2; }
  int i2 = 255 - (int)(k2 & 0xFFull);

  double p1 = __shfl(p, tg * 16 + i1, 64);
  double p2 = __shfl(p, tg * 16 + i2, 64);

  sel_out[(size_t)s * E_EXP + e] = (e == i1 || e == i2) ? 1.f : 0.f;
  if (e == 0) {
    double inv = 1.0 / (p1 + p2);
    TokenRec r; r.i1 = i1; r.i2 = i2; r.g1 = (float)(p1 * inv); r.g2 = (float)(p2 * inv);
    te[s] = r;
    atomicAdd(&hist_lds[i1], 1u);
    atomicAdd(&hist_lds[i2], 1u);
  }
  __syncthreads();
  if (t < E_EXP) {
    atomicAdd(&countsTot[t], hist_lds[t]);
    atomicAdd(&proxyTot[t], pr_lds[t]);
  }
}

// ---------------- dispatch: per-block independent prefix + slot build + loss -------
// Replaces stats + prefix_loss + listbuild with ONE kernel, no cross-block comms:
// block b re-histograms te[0, b*1024) (L2-hot, <=240 KB) for its own lbase.
__global__ __launch_bounds__(256) void k_dispatch(const TokenRec* __restrict__ te,
                                                  const unsigned int* __restrict__ countsTot,
                                                  const float* __restrict__ proxyTot,
                                                  unsigned int* __restrict__ offsets_g,
                                                  int* __restrict__ slot_token,
                                                  float* __restrict__ slot_gate,
                                                  int* __restrict__ tok_slot,
                                                  float* __restrict__ out_loss) {
  __shared__ unsigned int histb[E_EXP], lbase[E_EXP], lcur[E_EXP];
  int t = threadIdx.x, b = blockIdx.x;
  int base = b * 1024;
  if (t < E_EXP) { histb[t] = 0u; lcur[t] = 0u; }
  __syncthreads();
  for (int i = t; i < base; i += 256) {
    TokenRec r = te[i];
    atomicAdd(&histb[r.i1], 1u);
    atomicAdd(&histb[r.i2], 1u);
  }
  __syncthreads();
  if (t < E_EXP) {
    unsigned int off = 0;
    for (int e = 0; e < t; e++) off += countsTot[e];
    lbase[t] = off + histb[t];
    if (b == 0) offsets_g[t] = off;
  }
  if (b == 0 && t == 16) {
    float ls = 0.f;
    for (int e = 0; e < E_EXP; e++) ls += proxyTot[e] * (float)countsTot[e];
    out_loss[0] = ls * ((float)E_EXP / ((float)S_TOK * (float)S_TOK));
    out_loss[1] = 0.f;
  }
  __syncthreads();
  for (int i = t; i < 1024; i += 256) {
    int s = base + i;
    TokenRec r = te[s];
    unsigned int p1 = atomicAdd(&lcur[r.i1], 1u);
    int sl1 = (int)(lbase[r.i1] + p1);
    slot_token[sl1] = s; slot_gate[sl1] = r.g1;
    unsigned int p2 = atomicAdd(&lcur[r.i2], 1u);
    int sl2 = (int)(lbase[r.i2] + p2);
    slot_token[sl2] = s; slot_gate[sl2] = r.g2;
    tok_slot[2 * s] = sl1;
    tok_slot[2 * s + 1] = sl2;
  }
}

// ---------------- gather x rows -> fp8 compact activations (k-interleaved) ----------
// within each 64-k block: byte = q*16 + h*8 + j  <->  k = h*32 + q*8 + j
__global__ __launch_bounds__(256) void k_gather(const float* __restrict__ x,
                                                const int* __restrict__ slot_token,
                                                unsigned char* __restrict__ xg) {
  int idx = blockIdx.x * 256 + threadIdx.x;   // 32768 * 64
  int row = idx >> 6, t6 = idx & 63;
  int blk = t6 >> 3, q = (t6 >> 1) & 3, h = t6 & 1;
  int tkn = slot_token[row];
  const float* xp = x + (size_t)tkn * M_DIM + blk * 64 + h * 32 + q * 8;
  f32x4 v0 = *(const f32x4*)xp;
  f32x4 v1 = *(const f32x4*)(xp + 4);
  int b0 = pk8<false>(v0.x, v0.y, 0); b0 = pk8<true>(v0.z, v0.w, b0);
  int b1 = pk8<false>(v1.x, v1.y, 0); b1 = pk8<true>(v1.z, v1.w, b1);
  i32x2 o; o.x = b0; o.y = b1;
  *(i32x2*)&xg[(size_t)row * 512 + blk * 64 + q * 16 + h * 8] = o;
}

// ---------------- grouped GEMM (fp8, BK=64): 128x128 tile, async dbuf staging,
// XOR-swizzled 16-B segments (0 conflicts). SWAPPED operands: A=weights, B=acts.
// T4 counted-vmcnt schedule. EPILOGUE VIA LDS -> coalesced dwordx4 stores.
// mid: out = relu(in @ W^T + b) -> fp8 (pad cols zeroed)
__global__ __launch_bounds__(256, 3) void k_gemm_mid(const unsigned char* __restrict__ in,
                                                  const unsigned char* __restrict__ wt,
                                                  const float* __restrict__ bias,
                                                  unsigned char* __restrict__ out,
                                                  const unsigned int* __restrict__ offsets,
                                                  const unsigned int* __restrict__ counts,
                                                  int KP, int NP, int NREAL) {
  int e = blockIdx.z;
  int n_e = (int)counts[e];
  if (n_e == 0) return;
  int base = (int)offsets[e];
  int bn = blockIdx.y;
  __shared__ __align__(16) unsigned char As[2][128 * 64];  // 2 x 8 KB activations (+ epilogue tile)
  __shared__ __align__(16) unsigned char Bs[2][128 * 64];  // 2 x 8 KB weights
  int t = threadIdx.x;
  int w = t >> 6, l = t & 63;
  int wm = w & 1, wn = w >> 1;
  int lr = l & 15, lq = l >> 4;
  int r_ = l >> 2, s_ = l & 3;
  int s2 = s_ ^ ((r_ >> 1) & 3);               // swizzled source segment (16 B units)
  int rsw = (lq ^ ((lr >> 1) & 3)) * 16;       // read-side swizzled byte offset
  int c0 = 2 * w, c1 = 2 * w + 1;              // two 16-row chunks per wave

  unsigned char* dA0[2] = {&As[0][c0 * 1024], &As[1][c0 * 1024]};
  unsigned char* dA1[2] = {&As[0][c1 * 1024], &As[1][c1 * 1024]};
  unsigned char* dB0[2] = {&Bs[0][c0 * 1024], &Bs[1][c0 * 1024]};
  unsigned char* dB1[2] = {&Bs[0][c1 * 1024], &Bs[1][c1 * 1024]};

  const unsigned char* bW = wt + (size_t)e * NP * KP;
  const unsigned char* bs0 = bW + (size_t)(bn * 128 + c0 * 16 + r_) * KP + s2 * 16;
  const unsigned char* bs1 = bW + (size_t)(bn * 128 + c1 * 16 + r_) * KP + s2 * 16;
  int nk = KP >> 6;

  for (int bm = blockIdx.x; bm * 128 < n_e; bm += gridDim.x) {
    int ra = bm * 128 + c0 * 16 + r_; ra = (ra < n_e) ? ra : (n_e - 1);
    int rb = bm * 128 + c1 * 16 + r_; rb = (rb < n_e) ? rb : (n_e - 1);
    const unsigned char* a0 = in + (size_t)(base + ra) * KP + s2 * 16;
    const unsigned char* a1 = in + (size_t)(base + rb) * KP + s2 * 16;
    const unsigned char* b0 = bs0;
    const unsigned char* b1 = bs1;
    f32x4 acc[4][4];
#pragma unroll
    for (int i = 0; i < 4; i++)
#pragma unroll
      for (int j = 0; j < 4; j++) acc[i][j] = (f32x4){0.f, 0.f, 0.f, 0.f};

    // prologue: stage buf0 (4 loads in flight)
    ld_lds16(a0, dA0[0]); ld_lds16(a1, dA1[0]); ld_lds16(b0, dB0[0]); ld_lds16(b1, dB1[0]);
    a0 += 64; a1 += 64; b0 += 64; b1 += 64;

    for (int ks = 0; ks < nk; ks++) {
      int cb = ks & 1, nb = cb ^ 1;
      // stage next K-tile FIRST, then wait only for the previous 4 (buf[cb]).
      if (ks + 1 < nk) {
        ld_lds16(a0, dA0[nb]); ld_lds16(a1, dA1[nb]); ld_lds16(b0, dB0[nb]); ld_lds16(b1, dB1[nb]);
        a0 += 64; a1 += 64; b0 += 64; b1 += 64;
        barrier_vm4();
      } else {
        barrier_vm0();
      }
      lx2 af[4], wf[4];
#pragma unroll
      for (int mi = 0; mi < 4; mi++) af[mi] = *(const lx2*)&As[cb][(wm * 64 + mi * 16 + lr) * 64 + rsw];
#pragma unroll
      for (int ni = 0; ni < 4; ni++) wf[ni] = *(const lx2*)&Bs[cb][(wn * 64 + ni * 16 + lr) * 64 + rsw];
      __builtin_amdgcn_s_setprio(1);
#pragma unroll
      for (int ni = 0; ni < 4; ni++)
#pragma unroll
        for (int mi = 0; mi < 4; mi++) {
          acc[ni][mi] = __builtin_amdgcn_mfma_f32_16x16x32_fp8_fp8(wf[ni].x, af[mi].x, acc[ni][mi], 0, 0, 0);
          acc[ni][mi] = __builtin_amdgcn_mfma_f32_16x16x32_fp8_fp8(wf[ni].y, af[mi].y, acc[ni][mi], 0, 0, 0);
        }
      __builtin_amdgcn_s_setprio(0);
      barrier_lgkm0();
    }

    // ---- epilogue via LDS: pack quads -> swizzled LDS tile -> coalesced 16B stores
    unsigned char* eb = &As[0][0];   // 16 KB: [row 0..127][byte 0..127]
#pragma unroll
    for (int ni = 0; ni < 4; ni++) {
      int nl = wn * 64 + ni * 16 + lq * 4;       // local col (0..127), 4-aligned
      int n0 = bn * 128 + nl;                    // global col
      bool cok = n0 < NREAL;                     // NREAL % 4 == 0 -> whole quad in/out
      f32x4 bv = (f32x4){0.f, 0.f, 0.f, 0.f};
      if (cok) bv = *(const f32x4*)&bias[(size_t)e * NREAL + n0];
      int k6 = nl & 63;
      int off = ((nl >> 6) << 6) + ((k6 >> 3) & 3) * 16 + ((k6 >> 5) & 1) * 8 + (k6 & 7);
#pragma unroll
      for (int mi = 0; mi < 4; mi++) {
        int row = wm * 64 + mi * 16 + lr;        // local row 0..127
        unsigned int pkv = 0u;
        if (cok) {
          f32x4 v = acc[ni][mi];
          int p = pk8<false>(fmaxf(v.x + bv.x, 0.f), fmaxf(v.y + bv.y, 0.f), 0);
          p = pk8<true>(fmaxf(v.z + bv.z, 0.f), fmaxf(v.w + bv.w, 0.f), p);
          pkv = (unsigned int)p;
        }
        *(unsigned int*)&eb[row * 128 + (off ^ ((row & 7) << 4))] = pkv;
      }
    }
    barrier_lgkm0();   // tile complete in LDS
#pragma unroll
    for (int it = 0; it < 4; it++) {
      int idx = it * 256 + t;
      int row = idx >> 3, seg = idx & 7;
      uint4 val = *(const uint4*)&eb[row * 128 + ((seg * 16) ^ ((row & 7) << 4))];
      int m = bm * 128 + row;
      if (m < n_e)
        *(uint4*)&out[(size_t)(base + m) * NP + bn * 128 + seg * 16] = val;
    }
    __syncthreads();   // epilogue LDS reads done before next tile's staging overwrites As
  }
}

// fin: 128x64 tile, swapped operands; eo[slot] = gate * (h3 @ W4 + b4);
// each thread stores float4 (4 consecutive cols of one row). T4+T5 schedule.
__global__ __launch_bounds__(256, 4) void k_gemm_fin(const unsigned char* __restrict__ in,
                                                  const unsigned char* __restrict__ wt,
                                                  const float* __restrict__ bias,
                                                  float* __restrict__ eo,
                                                  const unsigned int* __restrict__ offsets,
                                                  const unsigned int* __restrict__ counts,
                                                  const float* __restrict__ slot_gate) {
  const int KP = 1024, NP = 256;
  int e = blockIdx.z;
  int n_e = (int)counts[e];
  if (n_e == 0) return;
  int base = (int)offsets[e];
  int bn = blockIdx.y;
  __shared__ __align__(16) unsigned char As[2][128 * 64];  // 2 x 8 KB activations
  __shared__ __align__(16) unsigned char Bs[2][64 * 64];   // 2 x 4 KB weights
  int t = threadIdx.x;
  int w = t >> 6, l = t & 63;
  int wm = w & 1, wn = w >> 1;
  int lr = l & 15, lq = l >> 4;
  int r_ = l >> 2, s_ = l & 3;
  int s2 = s_ ^ ((r_ >> 1) & 3);
  int rsw = (lq ^ ((lr >> 1) & 3)) * 16;
  int c0 = 2 * w, c1 = 2 * w + 1;

  unsigned char* dA0[2] = {&As[0][c0 * 1024], &As[1][c0 * 1024]};
  unsigned char* dA1[2] = {&As[0][c1 * 1024], &As[1][c1 * 1024]};
  unsigned char* dB[2]  = {&Bs[0][w * 1024], &Bs[1][w * 1024]};

  const unsigned char* bW = wt + (size_t)e * NP * KP;
  const unsigned char* bsrc = bW + (size_t)(bn * 64 + w * 16 + r_) * KP + s2 * 16;
  int nk = KP >> 6;

  for (int bm = blockIdx.x; bm * 128 < n_e; bm += gridDim.x) {
    int ra = bm * 128 + c0 * 16 + r_; ra = (ra < n_e) ? ra : (n_e - 1);
    int rb = bm * 128 + c1 * 16 + r_; rb = (rb < n_e) ? rb : (n_e - 1);
    const unsigned char* a0 = in + (size_t)(base + ra) * KP + s2 * 16;
    const unsigned char* a1 = in + (size_t)(base + rb) * KP + s2 * 16;
    const unsigned char* bq = bsrc;
    f32x4 acc[2][4];
#pragma unroll
    for (int i = 0; i < 2; i++)
#pragma unroll
      for (int j = 0; j < 4; j++) acc[i][j] = (f32x4){0.f, 0.f, 0.f, 0.f};

    ld_lds16(a0, dA0[0]); ld_lds16(a1, dA1[0]); ld_lds16(bq, dB[0]);
    a0 += 64; a1 += 64; bq += 64;

    for (int ks = 0; ks < nk; ks++) {
      int cb = ks & 1, nb = cb ^ 1;
      if (ks + 1 < nk) {
        ld_lds16(a0, dA0[nb]); ld_lds16(a1, dA1[nb]); ld_lds16(bq, dB[nb]);
        a0 += 64; a1 += 64; bq += 64;
        barrier_vm3();
      } else {
        barrier_vm0();
      }
      lx2 af[4], wf[2];
#pragma unroll
      for (int mi = 0; mi < 4; mi++) af[mi] = *(const lx2*)&As[cb][(wm * 64 + mi * 16 + lr) * 64 + rsw];
#pragma unroll
      for (int ni = 0; ni < 2; ni++) wf[ni] = *(const lx2*)&Bs[cb][(wn * 32 + ni * 16 + lr) * 64 + rsw];
      __builtin_amdgcn_s_setprio(1);
#pragma unroll
      for (int ni = 0; ni < 2; ni++)
#pragma unroll
        for (int mi = 0; mi < 4; mi++) {
          acc[ni][mi] = __builtin_amdgcn_mfma_f32_16x16x32_fp8_fp8(wf[ni].x, af[mi].x, acc[ni][mi], 0, 0, 0);
          acc[ni][mi] = __builtin_amdgcn_mfma_f32_16x16x32_fp8_fp8(wf[ni].y, af[mi].y, acc[ni][mi], 0, 0, 0);
        }
      __builtin_amdgcn_s_setprio(0);
      barrier_lgkm0();
    }

    int mbase = bm * 128 + wm * 64;
    int nbase = bn * 64 + wn * 32;
#pragma unroll
    for (int ni = 0; ni < 2; ni++) {
      int n0 = nbase + ni * 16 + lq * 4;
      f32x4 bv = *(const f32x4*)&bias[(size_t)e * 256 + n0];
#pragma unroll
      for (int mi = 0; mi < 4; mi++) {
        int m = mbase + mi * 16 + lr;
        if (m < n_e) {
          int gr = base + m;
          float g = slot_gate[gr];
          f32x4 v;
          v.x = g * (acc[ni][mi].x + bv.x);
          v.y = g * (acc[ni][mi].y + bv.y);
          v.z = g * (acc[ni][mi].z + bv.z);
          v.w = g * (acc[ni][mi].w + bv.w);
          *(f32x4*)&eo[(size_t)gr * NP + n0] = v;
        }
      }
    }
  }
}

// ---------------- combine: out[s] = eo[sl1(s)] + eo[sl2(s)] ----------------
__global__ __launch_bounds__(256) void k_combine(const float* __restrict__ eo,
                                                 const int* __restrict__ tok_slot,
                                                 float* __restrict__ out) {
  int idx = blockIdx.x * 256 + threadIdx.x;
  int s = idx >> 6, q = idx & 63;
  int sl1 = tok_slot[2 * s], sl2 = tok_slot[2 * s + 1];
  f32x4 v1 = *(const f32x4*)&eo[(size_t)sl1 * D_OUT + q * 4];
  f32x4 v2 = *(const f32x4*)&eo[(size_t)sl2 * D_OUT + q * 4];
  *(f32x4*)&out[(size_t)s * D_OUT + q * 4] = v1 + v2;
}

extern "C" void kernel_launch(void* const* d_in, const int* in_sizes, int n_in,
                              void* d_out, int out_size, void* d_ws, size_t ws_size,
                              hipStream_t stream) {
  const float* x    = (const float*)d_in[0];
  const float* nois = (const float*)d_in[1];
  const float* Wr   = (const float*)d_in[2];
  const float* W1   = (const float*)d_in[3];
  const float* b1   = (const float*)d_in[4];
  const float* W2   = (const float*)d_in[5];
  const float* b2   = (const float*)d_in[6];
  const float* W3   = (const float*)d_in[7];
  const float* b3   = (const float*)d_in[8];
  const float* W4   = (const float*)d_in[9];
  const float* b4   = (const float*)d_in[10];
  float* out = (float*)d_out;

  char* w = (char*)d_ws;
  unsigned char* actA = (unsigned char*)(w + 0);          // 32768*1024 fp8 = 33554432 B
  unsigned char* actB = (unsigned char*)(w + 33554432);   // 32768*512 fp8  = 16777216 B
  unsigned char* Wt1  = (unsigned char*)(w + 50331648);   // 16*512*512   = 4 MB
  unsigned char* Wt2  = (unsigned char*)(w + 54525952);   // 4 MB
  unsigned char* Wt3  = (unsigned char*)(w + 58720256);   // 16*1024*512  = 8 MB
  unsigned char* Wt4  = (unsigned char*)(w + 67108864);   // 16*256*1024  = 4 MB
  float*         eo   = (float*)(w + 71303168);           // 32768*256 f32 = 33554432 B
  int*           slot_token = (int*)(w + 104857600);      // 131072 B
  float*         slot_gate  = (float*)(w + 104988672);    // 131072 B
  TokenRec*      te         = (TokenRec*)(w + 105119744); // 262144 B
  unsigned int*  countsTot = (unsigned int*)(w + 105381888);  // 64 B (atomic)
  float*         proxyTot  = (float*)(w + 105381952);         // 64 B (atomic)
  unsigned int*  offsets = (unsigned int*)(w + 105382016);
  int*           tok_slot = (int*)(w + 105382080);        // 131072 B

  float* sel_out  = out + (size_t)S_TOK * D_OUT;
  float* loss_out = out + (size_t)S_TOK * D_OUT + (size_t)S_TOK * E_EXP;

  // zero the atomic accumulators (graph-capture-safe async memset)
  hipMemsetAsync(w + 105381888, 0, 128, stream);

  // fused (R5 layout): convw blocks 0..5119, router blocks 5120..6143
  k_router_convw<<<dim3(6144), dim3(256), 0, stream>>>(x, nois, Wr, sel_out, te,
                                                       W1, W2, W3, W4, Wt1, Wt2, Wt3, Wt4,
                                                       countsTot, proxyTot);

  // dispatch: replaces stats + prefix_loss + listbuild
  k_dispatch<<<dim3(16), dim3(256), 0, stream>>>(te, countsTot, proxyTot, offsets,
                                                 slot_token, slot_gate, tok_slot, loss_out);

  k_gather<<<dim3((2 * S_TOK * 64) / 256), dim3(256), 0, stream>>>(x, slot_token, actB);

  // Layer 1: [*,512] @ [512,500] -> relu -> actA (stride 512), 128x128 tiles
  k_gemm_mid<<<dim3(16, 4, E_EXP), dim3(256), 0, stream>>>(actB, Wt1, b1, actA, offsets, countsTot, 512, 512, H1D);
  // Layer 2: [*,500] @ [500,500] -> relu -> actB (stride 512)
  k_gemm_mid<<<dim3(16, 4, E_EXP), dim3(256), 0, stream>>>(actA, Wt2, b2, actB, offsets, countsTot, 512, 512, H2D);
  // Layer 3: [*,500] @ [500,1000] -> relu -> actA (stride 1024)
  k_gemm_mid<<<dim3(16, 8, E_EXP), dim3(256), 0, stream>>>(actB, Wt3, b3, actA, offsets, countsTot, 512, 1024, H3D);
  // Layer 4: [*,1000] @ [1000,256] -> eo[slot] = gate*(h3@W4+b4)   (128x64 tiles)
  k_gemm_fin<<<dim3(16, 4, E_EXP), dim3(256), 0, stream>>>(actA, Wt4, b4, eo, offsets, countsTot, slot_gate);
  // Combine: out[s] = eo[sl1] + eo[sl2]
  k_combine<<<dim3(S_TOK * 64 / 256), dim3(256), 0, stream>>>(eo, tok_slot, out);

  (void)in_sizes; (void)n_in; (void)out_size; (void)ws_size;
}

// Round 10
// 353.870 us; speedup vs baseline: 1.0940x; 1.0436x over previous
//
#include <hip/hip_runtime.h>
#include <stdint.h>

#define S_TOK 16384
#define M_DIM 512
#define E_EXP 16
#define D_OUT 256
#define H1D 500
#define H2D 500
#define H3D 1000

typedef float f32x4 __attribute__((ext_vector_type(4)));
typedef long lx2 __attribute__((ext_vector_type(2)));   // 16 B = two fp8 fragments
typedef int i32x2 __attribute__((ext_vector_type(2)));

template <bool HI>
__device__ __forceinline__ int pk8(float a, float b, int old) {
  return __builtin_amdgcn_cvt_pk_fp8_f32(a, b, old, HI);
}

// async global->LDS, 16B per lane; LDS dest = wave-uniform base + lane*16
__device__ __forceinline__ void ld_lds16(const unsigned char* g, unsigned char* l) {
  __builtin_amdgcn_global_load_lds(
      (const __attribute__((address_space(1))) unsigned int*)(const void*)g,
      (__attribute__((address_space(3))) unsigned int*)(void*)l, 16, 0, 0);
}

// fused waitcnt+barrier: nothing can slip between the count-wait and the barrier.
// Control flow is block-uniform at every call site.
__device__ __forceinline__ void barrier_vm4() { asm volatile("s_waitcnt vmcnt(4)\n\ts_barrier" ::: "memory"); }
__device__ __forceinline__ void barrier_vm3() { asm volatile("s_waitcnt vmcnt(3)\n\ts_barrier" ::: "memory"); }
__device__ __forceinline__ void barrier_vm0() { asm volatile("s_waitcnt vmcnt(0)\n\ts_barrier" ::: "memory"); }
__device__ __forceinline__ void barrier_lgkm0() { asm volatile("s_waitcnt lgkmcnt(0)\n\ts_barrier" ::: "memory"); }

struct TokenRec { int i1, i2; float g1, g2; };

// ---------------- FUSED router + weight-convert (independent workloads, one dispatch)
// blocks [0, 5120): convw (vectorized f32x4 loads), blocks [5120, 6144): router.
// This is the measured-best layout (353.9 us total, fused dispatch ~72 us).
__global__ __launch_bounds__(256) void k_router_convw(const float* __restrict__ x,
                                                      const float* __restrict__ noise,
                                                      const float* __restrict__ Wr,
                                                      float* __restrict__ sel_out,
                                                      float* __restrict__ sel_buf,
                                                      TokenRec* __restrict__ te,
                                                      const float* __restrict__ W1,
                                                      const float* __restrict__ W2,
                                                      const float* __restrict__ W3,
                                                      const float* __restrict__ W4,
                                                      unsigned char* __restrict__ D1,
                                                      unsigned char* __restrict__ D2,
                                                      unsigned char* __restrict__ D3,
                                                      unsigned char* __restrict__ D4) {
  __shared__ float smem[E_EXP * 516];   // 33 KB: router wr[] / convw tile[64][65]
  int t = threadIdx.x;

  if (blockIdx.x < 5120) {
    // ================= convw body =================
    float (*tile)[65] = (float(*)[65])smem;   // tile[k_local][n_local], pad 65
    int bid = blockIdx.x;
    int tb = bid % 320, e = bid / 320;
    const float* src; unsigned char* dst;
    int Kr, Nr, Kp, Np, kx, ny;
    if (tb < 64)        { src = W1; dst = D1; Kr = 512;  Nr = H1D; Kp = 512;  Np = 512;  kx = tb >> 3;  ny = tb & 7; }
    else if (tb < 128)  { tb -= 64;  src = W2; dst = D2; Kr = H1D; Nr = H2D; Kp = 512;  Np = 512;  kx = tb >> 3;  ny = tb & 7; }
    else if (tb < 256)  { tb -= 128; src = W3; dst = D3; Kr = H2D; Nr = H3D; Kp = 512;  Np = 1024; kx = tb >> 4;  ny = tb & 15; }
    else                { tb -= 256; src = W4; dst = D4; Kr = H3D; Nr = 256; Kp = 1024; Np = 256;  kx = tb >> 2;  ny = tb & 3; }
    int k0 = kx * 64, n0 = ny * 64;
    const float* sp = src + (size_t)e * Kr * Nr;
    // vectorized staging: 4 x f32x4 per thread (16 lanes x 4 floats = 64 n per row)
    int ry4 = t >> 4, cx4 = (t & 15) * 4;
#pragma unroll
    for (int i = 0; i < 4; i++) {
      int k = k0 + ry4 + i * 16, n = n0 + cx4;
      f32x4 v;
      if (k < Kr && n + 3 < Nr) {
        v = *(const f32x4*)&sp[(size_t)k * Nr + n];
      } else {
        v.x = (k < Kr && n + 0 < Nr) ? sp[(size_t)k * Nr + n + 0] : 0.f;
        v.y = (k < Kr && n + 1 < Nr) ? sp[(size_t)k * Nr + n + 1] : 0.f;
        v.z = (k < Kr && n + 2 < Nr) ? sp[(size_t)k * Nr + n + 2] : 0.f;
        v.w = (k < Kr && n + 3 < Nr) ? sp[(size_t)k * Nr + n + 3] : 0.f;
      }
      int r = ry4 + i * 16;
      tile[r][cx4 + 0] = v.x; tile[r][cx4 + 1] = v.y;
      tile[r][cx4 + 2] = v.z; tile[r][cx4 + 3] = v.w;
    }
    __syncthreads();
    int nl = t >> 2, q = t & 3;
    int b0 = pk8<false>(tile[q * 8 + 0][nl], tile[q * 8 + 1][nl], 0);
    b0 = pk8<true>(tile[q * 8 + 2][nl], tile[q * 8 + 3][nl], b0);
    int b1 = pk8<false>(tile[q * 8 + 4][nl], tile[q * 8 + 5][nl], 0);
    b1 = pk8<true>(tile[q * 8 + 6][nl], tile[q * 8 + 7][nl], b1);
    int c0 = pk8<false>(tile[32 + q * 8 + 0][nl], tile[32 + q * 8 + 1][nl], 0);
    c0 = pk8<true>(tile[32 + q * 8 + 2][nl], tile[32 + q * 8 + 3][nl], c0);
    int c1 = pk8<false>(tile[32 + q * 8 + 4][nl], tile[32 + q * 8 + 5][nl], 0);
    c1 = pk8<true>(tile[32 + q * 8 + 6][nl], tile[32 + q * 8 + 7][nl], c1);
    uint4 pk; pk.x = (unsigned)b0; pk.y = (unsigned)b1; pk.z = (unsigned)c0; pk.w = (unsigned)c1;
    *(uint4*)&dst[(size_t)e * Np * Kp + (size_t)(n0 + nl) * Kp + k0 + q * 16] = pk;
    return;
  }

  // ================= router body =================
  float* wr = smem;                     // [E_EXP * 516], pad 516
  int rb = blockIdx.x - 5120;
  for (int i = t; i < E_EXP * M_DIM; i += 256) {
    int e = i >> 9, m = i & 511;
    wr[e * 516 + m] = Wr[i];
  }
  __syncthreads();

  int wv = t >> 6, l = t & 63;
  int e = l & 15, tg = l >> 4;
  int s = rb * 16 + wv * 4 + tg;

  const float* xr = x + (size_t)s * M_DIM;
  const float* wre = &wr[e * 516];
  double a0 = 0.0, a1 = 0.0, a2 = 0.0, a3 = 0.0;
#pragma unroll 4
  for (int m = 0; m < M_DIM; m += 4) {
    f32x4 xv = *(const f32x4*)(xr + m);
    f32x4 wv4 = *(const f32x4*)(wre + m);
    a0 += (double)xv.x * (double)wv4.x;
    a1 += (double)xv.y * (double)wv4.y;
    a2 += (double)xv.z * (double)wv4.z;
    a3 += (double)xv.w * (double)wv4.w;
  }
  double a = (a0 + a1) + (a2 + a3);
  a += (double)noise[(size_t)s * E_EXP + e];

  double mx = a;
#pragma unroll
  for (int off = 8; off >= 1; off >>= 1) { double o = __shfl_xor(mx, off, 64); mx = (o > mx) ? o : mx; }
  double p = exp(a - mx);
  double sum = p;
#pragma unroll
  for (int off = 8; off >= 1; off >>= 1) sum += __shfl_xor(sum, off, 64);
  sel_buf[(size_t)s * E_EXP + e] = (float)(p / sum);

  unsigned long long pb = __double_as_longlong(p);
  unsigned long long key = (pb & ~0xFFull) | (unsigned long long)(255 - e);
  unsigned long long k1 = key;
#pragma unroll
  for (int off = 8; off >= 1; off >>= 1) { unsigned long long o = __shfl_xor(k1, off, 64); k1 = (o > k1) ? o : k1; }
  int i1 = 255 - (int)(k1 & 0xFFull);
  unsigned long long key2 = (e == i1) ? 0ull : key;
  unsigned long long k2 = key2;
#pragma unroll
  for (int off = 8; off >= 1; off >>= 1) { unsigned long long o = __shfl_xor(k2, off, 64); k2 = (o > k2) ? o : k2; }
  int i2 = 255 - (int)(k2 & 0xFFull);

  double p1 = __shfl(p, tg * 16 + i1, 64);
  double p2 = __shfl(p, tg * 16 + i2, 64);

  sel_out[(size_t)s * E_EXP + e] = (e == i1 || e == i2) ? 1.f : 0.f;
  if (e == 0) {
    double inv = 1.0 / (p1 + p2);
    TokenRec r; r.i1 = i1; r.i2 = i2; r.g1 = (float)(p1 * inv); r.g2 = (float)(p2 * inv);
    te[s] = r;
  }
}

// ---------------- stats: per-block proxy partial sums + histogram ----------------
__global__ __launch_bounds__(256) void k_stats(const float* __restrict__ sel_buf,
                                               const TokenRec* __restrict__ te,
                                               float* __restrict__ partials) {  // [16][32]
  __shared__ float psum[256];
  __shared__ unsigned int hist[E_EXP];
  int t = threadIdx.x, b = blockIdx.x;
  if (t < E_EXP) hist[t] = 0u;
  __syncthreads();
  int e = t & 15, rg = t >> 4;
  int base = b * 1024;
  float acc = 0.f;
#pragma unroll 4
  for (int i = 0; i < 64; i++)
    acc += sel_buf[(size_t)(base + i * 16 + rg) * E_EXP + e];
  for (int i = t; i < 1024; i += 256) {
    TokenRec r = te[base + i];
    atomicAdd(&hist[r.i1], 1u);
    atomicAdd(&hist[r.i2], 1u);
  }
  psum[t] = acc;
  __syncthreads();
  if (t < E_EXP) {
    float v = 0.f;
#pragma unroll
    for (int rg2 = 0; rg2 < 16; rg2++) v += psum[rg2 * 16 + t];
    partials[b * 32 + t] = v;
    partials[b * 32 + 16 + t] = (float)hist[t];
  }
}

// ---------------- reduce partials -> counts/offsets + balance loss + cursor init ------
__global__ void k_prefix_loss(const float* __restrict__ partials,
                              unsigned int* __restrict__ counts,
                              unsigned int* __restrict__ offsets,
                              unsigned int* __restrict__ cursor,
                              float* __restrict__ out_loss) {
  __shared__ float pr[E_EXP];
  __shared__ unsigned int cn[E_EXP];
  int t = threadIdx.x;
  if (t < E_EXP) {
    float p = 0.f, c = 0.f;
    for (int b = 0; b < 16; b++) { p += partials[b * 32 + t]; c += partials[b * 32 + 16 + t]; }
    pr[t] = p; cn[t] = (unsigned int)(c + 0.5f);
    cursor[t] = 0u;
  }
  __syncthreads();
  if (t == 0) {
    unsigned int acc = 0; float ls = 0.f;
    for (int e = 0; e < E_EXP; e++) {
      counts[e] = cn[e];
      offsets[e] = acc;
      acc += cn[e];
      ls += pr[e] * (float)cn[e];
    }
    out_loss[0] = ls * ((float)E_EXP / ((float)S_TOK * (float)S_TOK));
    out_loss[1] = 0.f;
  }
}

// ---------------- listbuild: block-level reservation + inverse map ----------------
__global__ __launch_bounds__(256) void k_listbuild(const TokenRec* __restrict__ te,
                                                   const unsigned int* __restrict__ offsets,
                                                   unsigned int* __restrict__ cursor,
                                                   int* __restrict__ slot_token,
                                                   float* __restrict__ slot_gate,
                                                   int* __restrict__ tok_slot) {
  __shared__ unsigned int lhist[E_EXP];
  __shared__ unsigned int lbase[E_EXP];
  __shared__ unsigned int lcur[E_EXP];
  int t = threadIdx.x, b = blockIdx.x;
  int base = b * 1024;
  if (t < E_EXP) lhist[t] = 0u;
  __syncthreads();
  for (int i = t; i < 1024; i += 256) {
    TokenRec r = te[base + i];
    atomicAdd(&lhist[r.i1], 1u);
    atomicAdd(&lhist[r.i2], 1u);
  }
  __syncthreads();
  if (t < E_EXP) {
    lbase[t] = offsets[t] + atomicAdd(&cursor[t], lhist[t]);
    lcur[t] = 0u;
  }
  __syncthreads();
  for (int i = t; i < 1024; i += 256) {
    int s = base + i;
    TokenRec r = te[s];
    unsigned int p1 = atomicAdd(&lcur[r.i1], 1u);
    int sl1 = (int)(lbase[r.i1] + p1);
    slot_token[sl1] = s; slot_gate[sl1] = r.g1;
    unsigned int p2 = atomicAdd(&lcur[r.i2], 1u);
    int sl2 = (int)(lbase[r.i2] + p2);
    slot_token[sl2] = s; slot_gate[sl2] = r.g2;
    tok_slot[2 * s] = sl1;
    tok_slot[2 * s + 1] = sl2;
  }
}

// ---------------- gather x rows -> fp8 compact activations (k-interleaved) ----------
// within each 64-k block: byte = q*16 + h*8 + j  <->  k = h*32 + q*8 + j
__global__ __launch_bounds__(256) void k_gather(const float* __restrict__ x,
                                                const int* __restrict__ slot_token,
                                                unsigned char* __restrict__ xg) {
  int idx = blockIdx.x * 256 + threadIdx.x;   // 32768 * 64
  int row = idx >> 6, t6 = idx & 63;
  int blk = t6 >> 3, q = (t6 >> 1) & 3, h = t6 & 1;
  int tkn = slot_token[row];
  const float* xp = x + (size_t)tkn * M_DIM + blk * 64 + h * 32 + q * 8;
  f32x4 v0 = *(const f32x4*)xp;
  f32x4 v1 = *(const f32x4*)(xp + 4);
  int b0 = pk8<false>(v0.x, v0.y, 0); b0 = pk8<true>(v0.z, v0.w, b0);
  int b1 = pk8<false>(v1.x, v1.y, 0); b1 = pk8<true>(v1.z, v1.w, b1);
  i32x2 o; o.x = b0; o.y = b1;
  *(i32x2*)&xg[(size_t)row * 512 + blk * 64 + q * 16 + h * 8] = o;
}

// ---------------- grouped GEMM (fp8, BK=64): 128x128 tile, async dbuf staging,
// XOR-swizzled 16-B segments (0 conflicts). SWAPPED operands: A=weights, B=acts.
// T4 counted-vmcnt schedule. EPILOGUE VIA LDS: the 128x128 fp8 tile is written to
// a row-XOR-swizzled LDS buffer (reusing As, 16 KB), then swept out with coalesced
// dwordx4 stores (full 128-B row segments, full cache lines).
// mid: out = relu(in @ W^T + b) -> fp8 (pad cols zeroed)
__global__ __launch_bounds__(256, 3) void k_gemm_mid(const unsigned char* __restrict__ in,
                                                  const unsigned char* __restrict__ wt,
                                                  const float* __restrict__ bias,
                                                  unsigned char* __restrict__ out,
                                                  const unsigned int* __restrict__ offsets,
                                                  const unsigned int* __restrict__ counts,
                                                  int KP, int NP, int NREAL) {
  int e = blockIdx.z;
  int n_e = (int)counts[e];
  if (n_e == 0) return;
  int base = (int)offsets[e];
  int bn = blockIdx.y;
  __shared__ __align__(16) unsigned char As[2][128 * 64];  // 2 x 8 KB activations (+ epilogue tile)
  __shared__ __align__(16) unsigned char Bs[2][128 * 64];  // 2 x 8 KB weights
  int t = threadIdx.x;
  int w = t >> 6, l = t & 63;
  int wm = w & 1, wn = w >> 1;
  int lr = l & 15, lq = l >> 4;
  int r_ = l >> 2, s_ = l & 3;
  int s2 = s_ ^ ((r_ >> 1) & 3);               // swizzled source segment (16 B units)
  int rsw = (lq ^ ((lr >> 1) & 3)) * 16;       // read-side swizzled byte offset
  int c0 = 2 * w, c1 = 2 * w + 1;              // two 16-row chunks per wave

  unsigned char* dA0[2] = {&As[0][c0 * 1024], &As[1][c0 * 1024]};
  unsigned char* dA1[2] = {&As[0][c1 * 1024], &As[1][c1 * 1024]};
  unsigned char* dB0[2] = {&Bs[0][c0 * 1024], &Bs[1][c0 * 1024]};
  unsigned char* dB1[2] = {&Bs[0][c1 * 1024], &Bs[1][c1 * 1024]};

  const unsigned char* bW = wt + (size_t)e * NP * KP;
  const unsigned char* bs0 = bW + (size_t)(bn * 128 + c0 * 16 + r_) * KP + s2 * 16;
  const unsigned char* bs1 = bW + (size_t)(bn * 128 + c1 * 16 + r_) * KP + s2 * 16;
  int nk = KP >> 6;

  for (int bm = blockIdx.x; bm * 128 < n_e; bm += gridDim.x) {
    int ra = bm * 128 + c0 * 16 + r_; ra = (ra < n_e) ? ra : (n_e - 1);
    int rb = bm * 128 + c1 * 16 + r_; rb = (rb < n_e) ? rb : (n_e - 1);
    const unsigned char* a0 = in + (size_t)(base + ra) * KP + s2 * 16;
    const unsigned char* a1 = in + (size_t)(base + rb) * KP + s2 * 16;
    const unsigned char* b0 = bs0;
    const unsigned char* b1 = bs1;
    f32x4 acc[4][4];
#pragma unroll
    for (int i = 0; i < 4; i++)
#pragma unroll
      for (int j = 0; j < 4; j++) acc[i][j] = (f32x4){0.f, 0.f, 0.f, 0.f};

    // prologue: stage buf0 (4 loads in flight)
    ld_lds16(a0, dA0[0]); ld_lds16(a1, dA1[0]); ld_lds16(b0, dB0[0]); ld_lds16(b1, dB1[0]);
    a0 += 64; a1 += 64; b0 += 64; b1 += 64;

    for (int ks = 0; ks < nk; ks++) {
      int cb = ks & 1, nb = cb ^ 1;
      // stage next K-tile FIRST, then wait only for the previous 4 (buf[cb]).
      // The 4 fresh loads stay in flight across the barrier (T4).
      if (ks + 1 < nk) {
        ld_lds16(a0, dA0[nb]); ld_lds16(a1, dA1[nb]); ld_lds16(b0, dB0[nb]); ld_lds16(b1, dB1[nb]);
        a0 += 64; a1 += 64; b0 += 64; b1 += 64;
        barrier_vm4();
      } else {
        barrier_vm0();
      }
      // buf[cb] fully staged by all waves
      lx2 af[4], wf[4];
#pragma unroll
      for (int mi = 0; mi < 4; mi++) af[mi] = *(const lx2*)&As[cb][(wm * 64 + mi * 16 + lr) * 64 + rsw];
#pragma unroll
      for (int ni = 0; ni < 4; ni++) wf[ni] = *(const lx2*)&Bs[cb][(wn * 64 + ni * 16 + lr) * 64 + rsw];
      __builtin_amdgcn_s_setprio(1);
#pragma unroll
      for (int ni = 0; ni < 4; ni++)
#pragma unroll
        for (int mi = 0; mi < 4; mi++) {
          acc[ni][mi] = __builtin_amdgcn_mfma_f32_16x16x32_fp8_fp8(wf[ni].x, af[mi].x, acc[ni][mi], 0, 0, 0);
          acc[ni][mi] = __builtin_amdgcn_mfma_f32_16x16x32_fp8_fp8(wf[ni].y, af[mi].y, acc[ni][mi], 0, 0, 0);
        }
      __builtin_amdgcn_s_setprio(0);
      // all waves done reading buf[cb] before it is overwritten next iter
      barrier_lgkm0();
    }

    // ---- epilogue via LDS: pack quads -> swizzled LDS tile -> coalesced 16B stores
    unsigned char* eb = &As[0][0];   // 16 KB: [row 0..127][byte 0..127]
#pragma unroll
    for (int ni = 0; ni < 4; ni++) {
      int nl = wn * 64 + ni * 16 + lq * 4;       // local col (0..127), 4-aligned
      int n0 = bn * 128 + nl;                    // global col
      bool cok = n0 < NREAL;                     // NREAL % 4 == 0 -> whole quad in/out
      f32x4 bv = (f32x4){0.f, 0.f, 0.f, 0.f};
      if (cok) bv = *(const f32x4*)&bias[(size_t)e * NREAL + n0];
      int k6 = nl & 63;
      int off = ((nl >> 6) << 6) + ((k6 >> 3) & 3) * 16 + ((k6 >> 5) & 1) * 8 + (k6 & 7);
#pragma unroll
      for (int mi = 0; mi < 4; mi++) {
        int row = wm * 64 + mi * 16 + lr;        // local row 0..127
        unsigned int pkv = 0u;
        if (cok) {
          f32x4 v = acc[ni][mi];
          int p = pk8<false>(fmaxf(v.x + bv.x, 0.f), fmaxf(v.y + bv.y, 0.f), 0);
          p = pk8<true>(fmaxf(v.z + bv.z, 0.f), fmaxf(v.w + bv.w, 0.f), p);
          pkv = (unsigned int)p;
        }
        *(unsigned int*)&eb[row * 128 + (off ^ ((row & 7) << 4))] = pkv;
      }
    }
    barrier_lgkm0();   // tile complete in LDS
    // coalesced sweep: 1024 x 16B; lanes cover consecutive segments -> full lines
#pragma unroll
    for (int it = 0; it < 4; it++) {
      int idx = it * 256 + t;
      int row = idx >> 3, seg = idx & 7;
      uint4 val = *(const uint4*)&eb[row * 128 + ((seg * 16) ^ ((row & 7) << 4))];
      int m = bm * 128 + row;
      if (m < n_e)
        *(uint4*)&out[(size_t)(base + m) * NP + bn * 128 + seg * 16] = val;
    }
    __syncthreads();   // epilogue LDS reads done before next tile's staging overwrites As
  }
}

// fin: 128x64 tile, swapped operands; eo[slot] = gate * (h3 @ W4 + b4);
// each thread stores float4 (4 consecutive cols of one row). T4+T5 schedule.
__global__ __launch_bounds__(256, 4) void k_gemm_fin(const unsigned char* __restrict__ in,
                                                  const unsigned char* __restrict__ wt,
                                                  const float* __restrict__ bias,
                                                  float* __restrict__ eo,
                                                  const unsigned int* __restrict__ offsets,
                                                  const unsigned int* __restrict__ counts,
                                                  const float* __restrict__ slot_gate) {
  const int KP = 1024, NP = 256;
  int e = blockIdx.z;
  int n_e = (int)counts[e];
  if (n_e == 0) return;
  int base = (int)offsets[e];
  int bn = blockIdx.y;
  __shared__ __align__(16) unsigned char As[2][128 * 64];  // 2 x 8 KB activations
  __shared__ __align__(16) unsigned char Bs[2][64 * 64];   // 2 x 4 KB weights
  int t = threadIdx.x;
  int w = t >> 6, l = t & 63;
  int wm = w & 1, wn = w >> 1;
  int lr = l & 15, lq = l >> 4;
  int r_ = l >> 2, s_ = l & 3;
  int s2 = s_ ^ ((r_ >> 1) & 3);
  int rsw = (lq ^ ((lr >> 1) & 3)) * 16;
  int c0 = 2 * w, c1 = 2 * w + 1;

  unsigned char* dA0[2] = {&As[0][c0 * 1024], &As[1][c0 * 1024]};
  unsigned char* dA1[2] = {&As[0][c1 * 1024], &As[1][c1 * 1024]};
  unsigned char* dB[2]  = {&Bs[0][w * 1024], &Bs[1][w * 1024]};

  const unsigned char* bW = wt + (size_t)e * NP * KP;
  const unsigned char* bsrc = bW + (size_t)(bn * 64 + w * 16 + r_) * KP + s2 * 16;
  int nk = KP >> 6;

  for (int bm = blockIdx.x; bm * 128 < n_e; bm += gridDim.x) {
    int ra = bm * 128 + c0 * 16 + r_; ra = (ra < n_e) ? ra : (n_e - 1);
    int rb = bm * 128 + c1 * 16 + r_; rb = (rb < n_e) ? rb : (n_e - 1);
    const unsigned char* a0 = in + (size_t)(base + ra) * KP + s2 * 16;
    const unsigned char* a1 = in + (size_t)(base + rb) * KP + s2 * 16;
    const unsigned char* bq = bsrc;
    f32x4 acc[2][4];
#pragma unroll
    for (int i = 0; i < 2; i++)
#pragma unroll
      for (int j = 0; j < 4; j++) acc[i][j] = (f32x4){0.f, 0.f, 0.f, 0.f};

    ld_lds16(a0, dA0[0]); ld_lds16(a1, dA1[0]); ld_lds16(bq, dB[0]);
    a0 += 64; a1 += 64; bq += 64;

    for (int ks = 0; ks < nk; ks++) {
      int cb = ks & 1, nb = cb ^ 1;
      if (ks + 1 < nk) {
        ld_lds16(a0, dA0[nb]); ld_lds16(a1, dA1[nb]); ld_lds16(bq, dB[nb]);
        a0 += 64; a1 += 64; bq += 64;
        barrier_vm3();
      } else {
        barrier_vm0();
      }
      lx2 af[4], wf[2];
#pragma unroll
      for (int mi = 0; mi < 4; mi++) af[mi] = *(const lx2*)&As[cb][(wm * 64 + mi * 16 + lr) * 64 + rsw];
#pragma unroll
      for (int ni = 0; ni < 2; ni++) wf[ni] = *(const lx2*)&Bs[cb][(wn * 32 + ni * 16 + lr) * 64 + rsw];
      __builtin_amdgcn_s_setprio(1);
#pragma unroll
      for (int ni = 0; ni < 2; ni++)
#pragma unroll
        for (int mi = 0; mi < 4; mi++) {
          acc[ni][mi] = __builtin_amdgcn_mfma_f32_16x16x32_fp8_fp8(wf[ni].x, af[mi].x, acc[ni][mi], 0, 0, 0);
          acc[ni][mi] = __builtin_amdgcn_mfma_f32_16x16x32_fp8_fp8(wf[ni].y, af[mi].y, acc[ni][mi], 0, 0, 0);
        }
      __builtin_amdgcn_s_setprio(0);
      barrier_lgkm0();
    }

    int mbase = bm * 128 + wm * 64;
    int nbase = bn * 64 + wn * 32;
#pragma unroll
    for (int ni = 0; ni < 2; ni++) {
      int n0 = nbase + ni * 16 + lq * 4;
      f32x4 bv = *(const f32x4*)&bias[(size_t)e * 256 + n0];
#pragma unroll
      for (int mi = 0; mi < 4; mi++) {
        int m = mbase + mi * 16 + lr;
        if (m < n_e) {
          int gr = base + m;
          float g = slot_gate[gr];
          f32x4 v;
          v.x = g * (acc[ni][mi].x + bv.x);
          v.y = g * (acc[ni][mi].y + bv.y);
          v.z = g * (acc[ni][mi].z + bv.z);
          v.w = g * (acc[ni][mi].w + bv.w);
          *(f32x4*)&eo[(size_t)gr * NP + n0] = v;
        }
      }
    }
  }
}

// ---------------- combine: out[s] = eo[sl1(s)] + eo[sl2(s)] ----------------
__global__ __launch_bounds__(256) void k_combine(const float* __restrict__ eo,
                                                 const int* __restrict__ tok_slot,
                                                 float* __restrict__ out) {
  int idx = blockIdx.x * 256 + threadIdx.x;
  int s = idx >> 6, q = idx & 63;
  int sl1 = tok_slot[2 * s], sl2 = tok_slot[2 * s + 1];
  f32x4 v1 = *(const f32x4*)&eo[(size_t)sl1 * D_OUT + q * 4];
  f32x4 v2 = *(const f32x4*)&eo[(size_t)sl2 * D_OUT + q * 4];
  *(f32x4*)&out[(size_t)s * D_OUT + q * 4] = v1 + v2;
}

extern "C" void kernel_launch(void* const* d_in, const int* in_sizes, int n_in,
                              void* d_out, int out_size, void* d_ws, size_t ws_size,
                              hipStream_t stream) {
  const float* x    = (const float*)d_in[0];
  const float* nois = (const float*)d_in[1];
  const float* Wr   = (const float*)d_in[2];
  const float* W1   = (const float*)d_in[3];
  const float* b1   = (const float*)d_in[4];
  const float* W2   = (const float*)d_in[5];
  const float* b2   = (const float*)d_in[6];
  const float* W3   = (const float*)d_in[7];
  const float* b3   = (const float*)d_in[8];
  const float* W4   = (const float*)d_in[9];
  const float* b4   = (const float*)d_in[10];
  float* out = (float*)d_out;

  char* w = (char*)d_ws;
  unsigned char* actA = (unsigned char*)(w + 0);          // 32768*1024 fp8 = 33554432 B
  unsigned char* actB = (unsigned char*)(w + 33554432);   // 32768*512 fp8  = 16777216 B
  unsigned char* Wt1  = (unsigned char*)(w + 50331648);   // 16*512*512   = 4 MB
  unsigned char* Wt2  = (unsigned char*)(w + 54525952);   // 4 MB
  unsigned char* Wt3  = (unsigned char*)(w + 58720256);   // 16*1024*512  = 8 MB
  unsigned char* Wt4  = (unsigned char*)(w + 67108864);   // 16*256*1024  = 4 MB
  float*         eo   = (float*)(w + 71303168);           // 32768*256 f32 = 33554432 B
  int*           slot_token = (int*)(w + 104857600);      // 131072 B
  float*         slot_gate  = (float*)(w + 104988672);    // 131072 B
  TokenRec*      te         = (TokenRec*)(w + 105119744); // 262144 B
  unsigned int*  counts  = (unsigned int*)(w + 105381888);
  unsigned int*  cursor  = (unsigned int*)(w + 105381952);
  unsigned int*  offsets = (unsigned int*)(w + 105382016);
  int*           tok_slot = (int*)(w + 105382080);        // 131072 B
  // transient overlays on actA (dead before L1 GEMM writes actA)
  float*         sel_buf  = (float*)(w + 0);              // 1 MB
  float*         partials = (float*)(w + 1048576);        // 2 KB

  float* sel_out  = out + (size_t)S_TOK * D_OUT;
  float* loss_out = out + (size_t)S_TOK * D_OUT + (size_t)S_TOK * E_EXP;

  // fused: weight-convert (blocks 0..5119, long pole first) + router (blocks 5120..6143)
  k_router_convw<<<dim3(6144), dim3(256), 0, stream>>>(x, nois, Wr, sel_out, sel_buf, te,
                                                       W1, W2, W3, W4, Wt1, Wt2, Wt3, Wt4);

  k_stats<<<dim3(16), dim3(256), 0, stream>>>(sel_buf, te, partials);
  k_prefix_loss<<<dim3(1), dim3(64), 0, stream>>>(partials, counts, offsets, cursor, loss_out);
  k_listbuild<<<dim3(16), dim3(256), 0, stream>>>(te, offsets, cursor, slot_token, slot_gate, tok_slot);
  k_gather<<<dim3((2 * S_TOK * 64) / 256), dim3(256), 0, stream>>>(x, slot_token, actB);

  // Layer 1: [*,512] @ [512,500] -> relu -> actA (stride 512), 128x128 tiles
  k_gemm_mid<<<dim3(16, 4, E_EXP), dim3(256), 0, stream>>>(actB, Wt1, b1, actA, offsets, counts, 512, 512, H1D);
  // Layer 2: [*,500] @ [500,500] -> relu -> actB (stride 512)
  k_gemm_mid<<<dim3(16, 4, E_EXP), dim3(256), 0, stream>>>(actA, Wt2, b2, actB, offsets, counts, 512, 512, H2D);
  // Layer 3: [*,500] @ [500,1000] -> relu -> actA (stride 1024)
  k_gemm_mid<<<dim3(16, 8, E_EXP), dim3(256), 0, stream>>>(actB, Wt3, b3, actA, offsets, counts, 512, 1024, H3D);
  // Layer 4: [*,1000] @ [1000,256] -> eo[slot] = gate*(h3@W4+b4)   (128x64 tiles)
  k_gemm_fin<<<dim3(16, 4, E_EXP), dim3(256), 0, stream>>>(actA, Wt4, b4, eo, offsets, counts, slot_gate);
  // Combine: out[s] = eo[sl1] + eo[sl2]
  k_combine<<<dim3(S_TOK * 64 / 256), dim3(256), 0, stream>>>(eo, tok_slot, out);

  (void)in_sizes; (void)n_in; (void)out_size; (void)ws_size;
}